// Round 1
// baseline (5001.210 us; speedup 1.0000x reference)
//
#include <hip/hip_runtime.h>
#include <hip/hip_bf16.h>

// Model dims
#define BB 32
#define QL_ 20
#define DL_ 64
#define BL_ 512
#define MN_ 8
#define ML_ 16
#define DD 128
#define HH 8

// ---------------- embedding gather: out[r,:] = emb[idx[r],:] ----------------
__global__ __launch_bounds__(256) void gather_embed(const int* __restrict__ idx,
                                                    const float* __restrict__ emb,
                                                    float* __restrict__ out, int rows) {
    int t = blockIdx.x * 256 + threadIdx.x;
    int total = rows * 32;                 // 32 float4 per 128-float row
    if (t >= total) return;
    int r = t >> 5, c = t & 31;
    const float4* e4 = (const float4*)(emb + (size_t)idx[r] * DD);
    ((float4*)(out + (size_t)r * DD))[c] = e4[c];
}

// ---------------- linear 128->128 + relu: out[r,o]=relu(b[o]+sum_e in[r,e]W[o,e]) ----
#define LIN_ROWS 32
__global__ __launch_bounds__(256) void linear128_relu(const float* __restrict__ in,
                                                      const float* __restrict__ W,
                                                      const float* __restrict__ bias,
                                                      float* __restrict__ out, int R) {
    __shared__ float wT[DD * DD];          // transposed: wT[e*128+o] = W[o*128+e]
    int tid = threadIdx.x;
    for (int i = tid; i < DD * DD; i += 256) {
        int o = i & 127, e = i >> 7;
        wT[e * DD + o] = W[o * DD + e];    // coalesced LDS writes, strided global reads (cached)
    }
    __syncthreads();
    int base = blockIdx.x * LIN_ROWS;
    int half = tid >> 7, o = tid & 127;
    for (int rr = 0; rr < LIN_ROWS; rr += 2) {
        int r = base + rr + half;
        if (r < R) {
            const float* x = in + (size_t)r * DD;
            float acc = bias[o];
#pragma unroll 8
            for (int e = 0; e < DD; e++) acc = fmaf(x[e], wT[e * DD + o], acc);
            out[(size_t)r * DD + o] = fmaxf(acc, 0.0f);
        }
    }
}

// ---------------- attention: one wave per (b,h,q-row), online softmax ----------------
template <int KPL>
__global__ __launch_bounds__(256) void attn_kernel(const float* __restrict__ q,
                                                   const float* __restrict__ k,
                                                   const float* __restrict__ v,
                                                   float* __restrict__ y, int L, int nWaves) {
    int wid = (blockIdx.x * 256 + threadIdx.x) >> 6;
    int lane = threadIdx.x & 63;
    if (wid >= nWaves) return;            // wave-uniform exit
    int qi = wid % L;
    int bh = wid / L;
    int h = bh & 7, b = bh >> 3;
    const float* qp = q + ((size_t)(b * L + qi) * DD + h * 16);
    float qv[16];
#pragma unroll
    for (int e = 0; e < 16; e++) qv[e] = qp[e];
    float s[KPL];
    float mx = -1e30f;
#pragma unroll
    for (int j = 0; j < KPL; j++) {
        int ki = j * 64 + lane;
        const float* kp = k + ((size_t)(b * L + ki) * DD + h * 16);
        float d = 0.f;
#pragma unroll
        for (int e = 0; e < 16; e++) d = fmaf(qv[e], kp[e], d);
        d *= 0.25f;                        // 1/sqrt(16)
        s[j] = d;
        mx = fmaxf(mx, d);
    }
    for (int off = 32; off; off >>= 1) mx = fmaxf(mx, __shfl_xor(mx, off, 64));
    float se = 0.f;
#pragma unroll
    for (int j = 0; j < KPL; j++) { float p = __expf(s[j] - mx); s[j] = p; se += p; }
    for (int off = 32; off; off >>= 1) se += __shfl_xor(se, off, 64);
    float acc[16];
#pragma unroll
    for (int e = 0; e < 16; e++) acc[e] = 0.f;
#pragma unroll
    for (int j = 0; j < KPL; j++) {
        int ki = j * 64 + lane;
        const float* vp = v + ((size_t)(b * L + ki) * DD + h * 16);
#pragma unroll
        for (int e = 0; e < 16; e++) acc[e] = fmaf(s[j], vp[e], acc[e]);
    }
#pragma unroll
    for (int e = 0; e < 16; e++)
        for (int off = 32; off; off >>= 1) acc[e] += __shfl_xor(acc[e], off, 64);
    if (lane == 0) {
        float* yp = y + ((size_t)(b * L + qi) * DD + h * 16);
        float inv = 1.0f / se;
#pragma unroll
        for (int e = 0; e < 16; e++) yp[e] = acc[e] * inv;
    }
}

// ---------------- row inverse norms: inv[r] = 1/max(||row||,1e-12) ----------------
__global__ __launch_bounds__(256) void rownorm(const float* __restrict__ in,
                                               float* __restrict__ inv, int R) {
    int w = (blockIdx.x * 256 + threadIdx.x) >> 6;
    int lane = threadIdx.x & 63;
    if (w >= R) return;
    const float* x = in + (size_t)w * DD;
    float a = x[lane], b = x[lane + 64];
    float ss = a * a + b * b;
    for (int off = 32; off; off >>= 1) ss += __shfl_xor(ss, off, 64);
    if (lane == 0) inv[w] = 1.0f / fmaxf(sqrtf(ss), 1e-12f);
}

// ---------------- KNRM log-sum: out[b,k] per batch block ----------------
__global__ __launch_bounds__(256) void knrm_kernel(
    const float* __restrict__ Q, const float* __restrict__ invQ, const float* __restrict__ mq, int QL,
    const float* __restrict__ Dm, const float* __restrict__ invD, const float* __restrict__ md,
    int DL, int DBS, int DOFF, float* __restrict__ out) {
    __shared__ float dtile[32 * DD];
    __shared__ float mdv[32];
    __shared__ float red[256];
    const float MUc[11] = {1.0f, 0.9f, 0.7f, 0.5f, 0.3f, 0.1f, -0.1f, -0.3f, -0.5f, -0.7f, -0.9f};
    const float NC[11]  = {-500000.0f, -50.f, -50.f, -50.f, -50.f, -50.f, -50.f, -50.f, -50.f, -50.f, -50.f};
    int b = blockIdx.x, tid = threadIdx.x;
    float ps[2][11];
#pragma unroll
    for (int j = 0; j < 2; j++)
#pragma unroll
        for (int kk = 0; kk < 11; kk++) ps[j][kk] = 0.f;

    for (int c0 = 0; c0 < DL; c0 += 32) {
        int cnt = min(32, DL - c0);
        for (int i = tid; i < cnt * DD; i += 256) {
            int dd = i >> 7, e = i & 127;
            int row = b * DBS + DOFF + c0 + dd;
            dtile[dd * DD + e] = Dm[(size_t)row * DD + e] * invD[row];  // prescale by 1/||d||
        }
        if (tid < cnt) mdv[tid] = md[b * DBS + DOFF + c0 + tid];
        __syncthreads();
#pragma unroll
        for (int j = 0; j < 2; j++) {
            int qi = tid + j * 256;
            if (qi < QL) {
                const float* qrow = Q + (size_t)(b * QL + qi) * DD;
                float iq = invQ[b * QL + qi];
                for (int d = 0; d < cnt; d++) {
                    float dot = 0.f;
#pragma unroll 8
                    for (int e = 0; e < DD; e++) dot = fmaf(qrow[e], dtile[d * DD + e], dot);
                    float sim = dot * iq;
                    float m = mdv[d];
#pragma unroll
                    for (int kk = 0; kk < 11; kk++) {
                        float df = sim - MUc[kk];
                        ps[j][kk] += __expf(df * df * NC[kk]) * m;
                    }
                }
            }
        }
        __syncthreads();
    }
    float acc[11];
#pragma unroll
    for (int kk = 0; kk < 11; kk++) acc[kk] = 0.f;
#pragma unroll
    for (int j = 0; j < 2; j++) {
        int qi = tid + j * 256;
        if (qi < QL) {
            float mv = mq[b * QL + qi] * 0.01f;
#pragma unroll
            for (int kk = 0; kk < 11; kk++) acc[kk] += logf(fmaxf(ps[j][kk], 1e-10f)) * mv;
        }
    }
    for (int kk = 0; kk < 11; kk++) {
        red[tid] = acc[kk];
        __syncthreads();
        for (int s = 128; s; s >>= 1) {
            if (tid < s) red[tid] += red[tid + s];
            __syncthreads();
        }
        if (tid == 0) out[b * 11 + kk] = red[0];
        __syncthreads();
    }
}

// ---------------- final combine: per-b scalar chain ----------------
__device__ inline float dot11(const float* w, const float* x) {
    float s = 0.f;
#pragma unroll
    for (int k = 0; k < 11; k++) s += w[k] * x[k];
    return s;
}

__global__ void final_kernel(const float* __restrict__ qdk, const float* __restrict__ qbk,
                             const float* __restrict__ kq, const float* __restrict__ kd,
                             const float* __restrict__ kb,
                             const float* qdW, const float* qdb, const float* qbW, const float* qbb,
                             const float* qcqW, const float* qcqb, const float* dcqW, const float* dcqb,
                             const float* bcqW, const float* bcqb, const float* expW, const float* expb,
                             const float* combW, const float* combb, float* __restrict__ out) {
    int b = threadIdx.x;
    if (b >= BB) return;
    float qd = tanhf(dot11(qdW, qdk + b * 11) + qdb[0]);
    float qb = tanhf(dot11(qbW, qbk + b * 11) + qbb[0]);
    float qcqd = 0.f, qcqb2 = 0.f;
    for (int i = 0; i < MN_; i++) {
        int base = (i * BB + b) * 11;
        float r  = tanhf(dot11(qcqW, kq + base) + qcqb[0]);
        float da = tanhf(dot11(dcqW, kd + base) + dcqb[0]);
        float ba = tanhf(dot11(bcqW, kb + base) + bcqb[0]);
        qcqd += r * da;
        qcqb2 += r * ba;
    }
    float qcq = expW[0] * qcqd + expW[1] * qcqb2 + expb[0];
    out[b] = tanhf(combW[0] * qd + combW[1] * qb + combW[2] * qcq + combb[0]);
}

extern "C" void kernel_launch(void* const* d_in, const int* in_sizes, int n_in,
                              void* d_out, int out_size, void* d_ws, size_t ws_size,
                              hipStream_t stream) {
    // setup_inputs() dict order
    const int*   in_q    = (const int*)d_in[0];
    const int*   in_d    = (const int*)d_in[1];
    const int*   in_dcq  = (const int*)d_in[2];
    const int*   in_db   = (const int*)d_in[3];
    const float* mask_q  = (const float*)d_in[4];
    const float* mask_d  = (const float*)d_in[5];
    const float* mask_dcq= (const float*)d_in[6];
    const float* mask_db = (const float*)d_in[7];
    const float* emb     = (const float*)d_in[8];
    const float* Wq = (const float*)d_in[9];   const float* bq = (const float*)d_in[10];
    const float* Wk = (const float*)d_in[11];  const float* bk = (const float*)d_in[12];
    const float* Wv = (const float*)d_in[13];  const float* bv = (const float*)d_in[14];
    const float* Wo = (const float*)d_in[15];  const float* bo = (const float*)d_in[16];
    const float* tW = (const float*)d_in[17];  const float* tb = (const float*)d_in[18];
    const float* qdW = (const float*)d_in[19]; const float* qdb = (const float*)d_in[20];
    const float* qbW = (const float*)d_in[21]; const float* qbb = (const float*)d_in[22];
    const float* qcqW = (const float*)d_in[23];const float* qcqb = (const float*)d_in[24];
    const float* dcqW = (const float*)d_in[25];const float* dcqb = (const float*)d_in[26];
    const float* bcqW = (const float*)d_in[27];const float* bcqb = (const float*)d_in[28];
    const float* expW = (const float*)d_in[29];const float* expb = (const float*)d_in[30];
    const float* combW = (const float*)d_in[31];const float* combb = (const float*)d_in[32];
    float* out = (float*)d_out;

    // workspace layout (floats)
    float* ws = (float*)d_ws;
    size_t off = 0;
    auto alloc = [&](size_t n) { float* p = ws + off; off += n; return p; };
    float* eq      = alloc((size_t)BB * QL_ * DD);   // 81920
    float* ed      = alloc((size_t)BB * DL_ * DD);   // 262144
    float* eb      = alloc((size_t)BB * BL_ * DD);   // 2097152
    float* edcq    = alloc((size_t)BB * MN_ * ML_ * DD); // 524288
    float* enc_d   = alloc((size_t)BB * DL_ * DD);
    float* enc_b   = alloc((size_t)BB * BL_ * DD);
    float* enc_dcq = alloc((size_t)BB * MN_ * ML_ * DD);
    float* qbuf    = alloc((size_t)BB * BL_ * DD);
    float* kbuf    = alloc((size_t)BB * BL_ * DD);
    float* vbuf    = alloc((size_t)BB * BL_ * DD);
    float* ybuf    = alloc((size_t)BB * BL_ * DD);
    float* inv_eq     = alloc(BB * QL_);
    float* inv_ed     = alloc(BB * DL_);
    float* inv_eb     = alloc(BB * BL_);
    float* inv_encd   = alloc(BB * DL_);
    float* inv_encb   = alloc(BB * BL_);
    float* inv_encdcq = alloc(BB * MN_ * ML_);
    float* qdk = alloc(BB * 11);
    float* qbk = alloc(BB * 11);
    float* kq  = alloc(MN_ * BB * 11);
    float* kd  = alloc(MN_ * BB * 11);
    float* kb  = alloc(MN_ * BB * 11);
    (void)ws_size; (void)in_sizes; (void)n_in; (void)out_size;

    // 1. embedding gathers
    gather_embed<<<(BB * QL_ * 32 + 255) / 256, 256, 0, stream>>>(in_q, emb, eq, BB * QL_);
    gather_embed<<<(BB * DL_ * 32 + 255) / 256, 256, 0, stream>>>(in_d, emb, ed, BB * DL_);
    gather_embed<<<(BB * BL_ * 32 + 255) / 256, 256, 0, stream>>>(in_db, emb, eb, BB * BL_);
    // dcq tokens -> ybuf (tmp), then t-projection + relu -> edcq
    gather_embed<<<(BB * MN_ * ML_ * 32 + 255) / 256, 256, 0, stream>>>(in_dcq, emb, ybuf, BB * MN_ * ML_);
    linear128_relu<<<(BB * MN_ * ML_ + LIN_ROWS - 1) / LIN_ROWS, 256, 0, stream>>>(ybuf, tW, tb, edcq, BB * MN_ * ML_);

    // 2. MHA x3
    auto mha = [&](const float* x, float* outp, int L) {
        int R = BB * L;
        int gl = (R + LIN_ROWS - 1) / LIN_ROWS;
        linear128_relu<<<gl, 256, 0, stream>>>(x, Wq, bq, qbuf, R);
        linear128_relu<<<gl, 256, 0, stream>>>(x, Wk, bk, kbuf, R);
        linear128_relu<<<gl, 256, 0, stream>>>(x, Wv, bv, vbuf, R);
        int nW = BB * HH * L;
        int blocks = (nW + 3) / 4;
        if (L == 64)       attn_kernel<1><<<blocks, 256, 0, stream>>>(qbuf, kbuf, vbuf, ybuf, L, nW);
        else if (L == 128) attn_kernel<2><<<blocks, 256, 0, stream>>>(qbuf, kbuf, vbuf, ybuf, L, nW);
        else               attn_kernel<8><<<blocks, 256, 0, stream>>>(qbuf, kbuf, vbuf, ybuf, L, nW);
        linear128_relu<<<gl, 256, 0, stream>>>(ybuf, Wo, bo, outp, R);
    };
    mha(edcq, enc_dcq, MN_ * ML_);  // L=128
    mha(ed, enc_d, DL_);            // L=64
    mha(eb, enc_b, BL_);            // L=512

    // 3. row norms
    auto norms = [&](const float* x, float* inv, int R) {
        rownorm<<<(R * 64 + 255) / 256, 256, 0, stream>>>(x, inv, R);
    };
    norms(eq, inv_eq, BB * QL_);
    norms(ed, inv_ed, BB * DL_);
    norms(eb, inv_eb, BB * BL_);
    norms(enc_d, inv_encd, BB * DL_);
    norms(enc_b, inv_encb, BB * BL_);
    norms(enc_dcq, inv_encdcq, BB * MN_ * ML_);

    // 4. KNRM passes
    knrm_kernel<<<BB, 256, 0, stream>>>(eq, inv_eq, mask_q, QL_, ed, inv_ed, mask_d, DL_, DL_, 0, qdk);
    knrm_kernel<<<BB, 256, 0, stream>>>(eq, inv_eq, mask_q, QL_, eb, inv_eb, mask_db, BL_, BL_, 0, qbk);
    for (int i = 0; i < MN_; i++) {
        int doff = i * ML_;
        knrm_kernel<<<BB, 256, 0, stream>>>(eq, inv_eq, mask_q, QL_,
                                            enc_dcq, inv_encdcq, mask_dcq, ML_, MN_ * ML_, doff,
                                            kq + (size_t)i * BB * 11);
        knrm_kernel<<<BB, 256, 0, stream>>>(enc_d, inv_encd, mask_d, DL_,
                                            enc_dcq, inv_encdcq, mask_dcq, ML_, MN_ * ML_, doff,
                                            kd + (size_t)i * BB * 11);
        knrm_kernel<<<BB, 256, 0, stream>>>(enc_b, inv_encb, mask_db, BL_,
                                            enc_dcq, inv_encdcq, mask_dcq, ML_, MN_ * ML_, doff,
                                            kb + (size_t)i * BB * 11);
    }

    // 5. final combine
    final_kernel<<<1, 64, 0, stream>>>(qdk, qbk, kq, kd, kb,
                                       qdW, qdb, qbW, qbb, qcqW, qcqb, dcqW, dcqb,
                                       bcqW, bcqb, expW, expb, combW, combb, out);
}

// Round 2
// 571.402 us; speedup vs baseline: 8.7525x; 8.7525x over previous
//
#include <hip/hip_runtime.h>
#include <hip/hip_bf16.h>

// Model dims
#define BB 32
#define QL_ 20
#define DL_ 64
#define BL_ 512
#define MN_ 8
#define ML_ 16
#define DD 128
#define HH 8

// ---------------- zero small region ----------------
__global__ void zero_kernel(float* __restrict__ p, int n) {
    int i = blockIdx.x * 256 + threadIdx.x;
    if (i < n) p[i] = 0.0f;
}

// ---------------- embedding gather: out[r,:] = emb[idx[r],:] ----------------
__global__ __launch_bounds__(256) void gather_embed(const int* __restrict__ idx,
                                                    const float* __restrict__ emb,
                                                    float* __restrict__ out, int rows) {
    int t = blockIdx.x * 256 + threadIdx.x;
    int total = rows * 32;
    if (t >= total) return;
    int r = t >> 5, c = t & 31;
    const float4* e4 = (const float4*)(emb + (size_t)idx[r] * DD);
    ((float4*)(out + (size_t)r * DD))[c] = e4[c];
}

// ---------------- linear 128->128 + relu, 4x4 register tile ----------------
// block: 256 threads = 32 o-groups x 8 r-groups; 32 rows x 128 outs per block
__global__ __launch_bounds__(256) void linear_v2(const float* __restrict__ in,
                                                 const float* __restrict__ W,
                                                 const float* __restrict__ bias,
                                                 float* __restrict__ out, int R) {
    __shared__ float wT[128 * 132];   // wT[e*132+o], pad 132 keeps b128 reads 2-way max
    __shared__ float xs[32 * 128];
    __shared__ float bs[128];
    int t = threadIdx.x;
    // stage W transposed: coalesced global (consecutive e), 8-way LDS write conflict (cheap once)
    for (int i = t; i < DD * DD; i += 256) {
        int e = i & 127, o = i >> 7;
        wT[e * 132 + o] = W[o * DD + e];
    }
    if (t < 128) bs[t] = bias[t];
    int base = blockIdx.x * 32;
    for (int i = t; i < 32 * 32; i += 256) {
        int r = i >> 5, c = i & 31;
        ((float4*)xs)[r * 32 + c] = ((const float4*)(in + (size_t)(base + r) * DD))[c];
    }
    __syncthreads();
    int og = t & 31, rg = t >> 5;           // o4 = og*4, rows 4*rg..4*rg+3
    float acc[4][4];
#pragma unroll
    for (int i = 0; i < 4; i++)
#pragma unroll
        for (int m = 0; m < 4; m++) acc[i][m] = 0.f;
#pragma unroll 4
    for (int e = 0; e < 128; e++) {
        float4 wv = *(const float4*)&wT[e * 132 + 4 * og];
        float x0 = xs[(4 * rg + 0) * 128 + e];
        float x1 = xs[(4 * rg + 1) * 128 + e];
        float x2 = xs[(4 * rg + 2) * 128 + e];
        float x3 = xs[(4 * rg + 3) * 128 + e];
        acc[0][0] = fmaf(x0, wv.x, acc[0][0]); acc[0][1] = fmaf(x0, wv.y, acc[0][1]);
        acc[0][2] = fmaf(x0, wv.z, acc[0][2]); acc[0][3] = fmaf(x0, wv.w, acc[0][3]);
        acc[1][0] = fmaf(x1, wv.x, acc[1][0]); acc[1][1] = fmaf(x1, wv.y, acc[1][1]);
        acc[1][2] = fmaf(x1, wv.z, acc[1][2]); acc[1][3] = fmaf(x1, wv.w, acc[1][3]);
        acc[2][0] = fmaf(x2, wv.x, acc[2][0]); acc[2][1] = fmaf(x2, wv.y, acc[2][1]);
        acc[2][2] = fmaf(x2, wv.z, acc[2][2]); acc[2][3] = fmaf(x2, wv.w, acc[2][3]);
        acc[3][0] = fmaf(x3, wv.x, acc[3][0]); acc[3][1] = fmaf(x3, wv.y, acc[3][1]);
        acc[3][2] = fmaf(x3, wv.z, acc[3][2]); acc[3][3] = fmaf(x3, wv.w, acc[3][3]);
    }
    float b0 = bs[4 * og], b1 = bs[4 * og + 1], b2 = bs[4 * og + 2], b3 = bs[4 * og + 3];
#pragma unroll
    for (int i = 0; i < 4; i++) {
        float4 o4;
        o4.x = fmaxf(acc[i][0] + b0, 0.f);
        o4.y = fmaxf(acc[i][1] + b1, 0.f);
        o4.z = fmaxf(acc[i][2] + b2, 0.f);
        o4.w = fmaxf(acc[i][3] + b3, 0.f);
        *(float4*)(out + (size_t)(base + 4 * rg + i) * DD + 4 * og) = o4;
    }
}

// ---------------- attention v2: block per (b,h), K/V slice in LDS ----------------
// softmax without max-subtraction: mathematically identical (shift-invariant), scores tiny.
template <int L, int NQ>
__global__ __launch_bounds__(256) void attn_v2(const float* __restrict__ q,
                                               const float* __restrict__ k,
                                               const float* __restrict__ v,
                                               float* __restrict__ y) {
    __shared__ float ks[L * 16];
    __shared__ float vs[L * 16];
    int bh = blockIdx.x;
    int h = bh & 7, b = bh >> 3;
    int t = threadIdx.x;
    const size_t base = (size_t)b * L * DD + h * 16;
    for (int i = t; i < L * 4; i += 256) {
        int j = i >> 2, c = i & 3;
        *(float4*)&ks[j * 16 + 4 * c] = *(const float4*)&k[base + (size_t)j * DD + 4 * c];
        *(float4*)&vs[j * 16 + 4 * c] = *(const float4*)&v[base + (size_t)j * DD + 4 * c];
    }
    __syncthreads();
    constexpr int ACT = L / NQ;
    if (t >= ACT) return;
    float qv[NQ][16], acc[NQ][16], l[NQ];
#pragma unroll
    for (int n = 0; n < NQ; n++) {
        const float* qp = q + base + (size_t)(t + n * ACT) * DD;
#pragma unroll
        for (int e = 0; e < 16; e++) { qv[n][e] = qp[e]; acc[n][e] = 0.f; }
        l[n] = 0.f;
    }
    for (int j = 0; j < L; j++) {
        float4 k0 = *(const float4*)&ks[j * 16];
        float4 k1 = *(const float4*)&ks[j * 16 + 4];
        float4 k2 = *(const float4*)&ks[j * 16 + 8];
        float4 k3 = *(const float4*)&ks[j * 16 + 12];
        float4 v0 = *(const float4*)&vs[j * 16];
        float4 v1 = *(const float4*)&vs[j * 16 + 4];
        float4 v2 = *(const float4*)&vs[j * 16 + 8];
        float4 v3 = *(const float4*)&vs[j * 16 + 12];
#pragma unroll
        for (int n = 0; n < NQ; n++) {
            float s = qv[n][0] * k0.x + qv[n][1] * k0.y + qv[n][2] * k0.z + qv[n][3] * k0.w
                    + qv[n][4] * k1.x + qv[n][5] * k1.y + qv[n][6] * k1.z + qv[n][7] * k1.w
                    + qv[n][8] * k2.x + qv[n][9] * k2.y + qv[n][10] * k2.z + qv[n][11] * k2.w
                    + qv[n][12] * k3.x + qv[n][13] * k3.y + qv[n][14] * k3.z + qv[n][15] * k3.w;
            float p = __expf(s * 0.25f);
            l[n] += p;
            acc[n][0] = fmaf(p, v0.x, acc[n][0]);   acc[n][1] = fmaf(p, v0.y, acc[n][1]);
            acc[n][2] = fmaf(p, v0.z, acc[n][2]);   acc[n][3] = fmaf(p, v0.w, acc[n][3]);
            acc[n][4] = fmaf(p, v1.x, acc[n][4]);   acc[n][5] = fmaf(p, v1.y, acc[n][5]);
            acc[n][6] = fmaf(p, v1.z, acc[n][6]);   acc[n][7] = fmaf(p, v1.w, acc[n][7]);
            acc[n][8] = fmaf(p, v2.x, acc[n][8]);   acc[n][9] = fmaf(p, v2.y, acc[n][9]);
            acc[n][10] = fmaf(p, v2.z, acc[n][10]); acc[n][11] = fmaf(p, v2.w, acc[n][11]);
            acc[n][12] = fmaf(p, v3.x, acc[n][12]); acc[n][13] = fmaf(p, v3.y, acc[n][13]);
            acc[n][14] = fmaf(p, v3.z, acc[n][14]); acc[n][15] = fmaf(p, v3.w, acc[n][15]);
        }
    }
#pragma unroll
    for (int n = 0; n < NQ; n++) {
        float inv = 1.0f / l[n];
        float* yp = y + base + (size_t)(t + n * ACT) * DD;
#pragma unroll
        for (int e = 0; e < 16; e++) yp[e] = acc[n][e] * inv;
    }
}

// ---------------- row inverse norms ----------------
__global__ __launch_bounds__(256) void rownorm(const float* __restrict__ in,
                                               float* __restrict__ inv, int R) {
    int w = (blockIdx.x * 256 + threadIdx.x) >> 6;
    int lane = threadIdx.x & 63;
    if (w >= R) return;
    const float* x = in + (size_t)w * DD;
    float a = x[lane], b = x[lane + 64];
    float ss = a * a + b * b;
    for (int off = 32; off; off >>= 1) ss += __shfl_xor(ss, off, 64);
    if (lane == 0) inv[w] = 1.0f / fmaxf(sqrtf(ss), 1e-12f);
}

// ---------------- KNRM core: register-tiled sims + gaussian kernels ----------------
// thread grid 16(tq) x 16(td); thread owns q rows tq+16*i (i<QPT), d rows td+16*j (j<DPT)
template <int QPT, int DPT>
__device__ void knrm_core(const float* __restrict__ Q, const float* __restrict__ invQ,
                          const float* __restrict__ mq, int QL, int q0, int qbase,
                          const float* __restrict__ D, const float* __restrict__ invD,
                          const float* __restrict__ md, int DL, int dbase, int mdbase,
                          float* __restrict__ out) {
    constexpr int QT = QPT * 16, DT = DPT * 16;
    __shared__ float qtile[QT * 132];
    __shared__ float dtile[DT * 132];
    __shared__ float mdv[DT];
    __shared__ float red[4][16][QPT * 11];
    __shared__ float outred[11];
    const float MUc[11] = {1.0f, 0.9f, 0.7f, 0.5f, 0.3f, 0.1f, -0.1f, -0.3f, -0.5f, -0.7f, -0.9f};
    const float NC[11]  = {-500000.0f, -50.f, -50.f, -50.f, -50.f, -50.f, -50.f, -50.f, -50.f, -50.f, -50.f};
    int t = threadIdx.x;
    int tq = t & 15, td = t >> 4;
    if (t < 11) outred[t] = 0.f;
    // stage q tile (prescaled by invQ, zero-padded)
    for (int i = t; i < QT * 32; i += 256) {
        int r = i >> 5, c = i & 31;
        int qrow = q0 + r;
        float4 val = make_float4(0.f, 0.f, 0.f, 0.f);
        if (qrow < QL) {
            float s = invQ[qbase + qrow];
            float4 g = *(const float4*)(Q + (size_t)(qbase + qrow) * DD + 4 * c);
            val = make_float4(g.x * s, g.y * s, g.z * s, g.w * s);
        }
        *(float4*)&qtile[r * 132 + 4 * c] = val;
    }
    float ps[QPT][11];
#pragma unroll
    for (int i = 0; i < QPT; i++)
#pragma unroll
        for (int kk = 0; kk < 11; kk++) ps[i][kk] = 0.f;

    for (int d0 = 0; d0 < DL; d0 += DT) {
        for (int i = t; i < DT * 32; i += 256) {
            int r = i >> 5, c = i & 31;
            int drow = d0 + r;
            float4 val = make_float4(0.f, 0.f, 0.f, 0.f);
            if (drow < DL) {
                float s = invD[dbase + drow];
                float4 g = *(const float4*)(D + (size_t)(dbase + drow) * DD + 4 * c);
                val = make_float4(g.x * s, g.y * s, g.z * s, g.w * s);
            }
            *(float4*)&dtile[r * 132 + 4 * c] = val;
        }
        if (t < DT) mdv[t] = (d0 + t < DL) ? md[mdbase + d0 + t] : 0.f;
        __syncthreads();
        float dot[QPT][DPT];
#pragma unroll
        for (int i = 0; i < QPT; i++)
#pragma unroll
            for (int j = 0; j < DPT; j++) dot[i][j] = 0.f;
#pragma unroll 2
        for (int e4 = 0; e4 < 32; e4++) {
            float4 qv[QPT], dv[DPT];
#pragma unroll
            for (int i = 0; i < QPT; i++) qv[i] = *(const float4*)&qtile[(tq + 16 * i) * 132 + 4 * e4];
#pragma unroll
            for (int j = 0; j < DPT; j++) dv[j] = *(const float4*)&dtile[(td + 16 * j) * 132 + 4 * e4];
#pragma unroll
            for (int i = 0; i < QPT; i++)
#pragma unroll
                for (int j = 0; j < DPT; j++)
                    dot[i][j] += qv[i].x * dv[j].x + qv[i].y * dv[j].y + qv[i].z * dv[j].z + qv[i].w * dv[j].w;
        }
#pragma unroll
        for (int j = 0; j < DPT; j++) {
            float m = mdv[td + 16 * j];
#pragma unroll
            for (int i = 0; i < QPT; i++) {
                float sim = dot[i][j];
#pragma unroll
                for (int kk = 0; kk < 11; kk++) {
                    float df = sim - MUc[kk];
                    ps[i][kk] = fmaf(__expf(df * df * NC[kk]), m, ps[i][kk]);
                }
            }
        }
        __syncthreads();
    }
    // reduce over td: intra-wave (td bits in lane bits 4,5), then cross-wave via LDS
#pragma unroll
    for (int i = 0; i < QPT; i++)
#pragma unroll
        for (int kk = 0; kk < 11; kk++) {
            ps[i][kk] += __shfl_xor(ps[i][kk], 16, 64);
            ps[i][kk] += __shfl_xor(ps[i][kk], 32, 64);
        }
    int w = t >> 6;
    if ((t & 63) < 16) {
#pragma unroll
        for (int i = 0; i < QPT; i++)
#pragma unroll
            for (int kk = 0; kk < 11; kk++) red[w][tq][i * 11 + kk] = ps[i][kk];
    }
    __syncthreads();
    for (int i = t; i < 16 * QPT * 11; i += 256) {
        int tq2 = i / (QPT * 11);
        int rem = i - tq2 * (QPT * 11);
        int qi = rem / 11, kk = rem - qi * 11;
        float s = red[0][tq2][qi * 11 + kk] + red[1][tq2][qi * 11 + kk]
                + red[2][tq2][qi * 11 + kk] + red[3][tq2][qi * 11 + kk];
        int qrow = q0 + tq2 + 16 * qi;
        if (qrow < QL) {
            float lps = logf(fmaxf(s, 1e-10f)) * mq[qbase + qrow] * 0.01f;
            atomicAdd(&outred[kk], lps);
        }
    }
    __syncthreads();
    if (t < 11) atomicAdd(&out[t], outred[t]);
}

// A: qd (eq x ed) and qb (eq x eb): 64 blocks
__global__ __launch_bounds__(256) void knrm_A(const float* eq, const float* inv_eq, const float* mask_q,
                                              const float* ed, const float* inv_ed, const float* mask_d,
                                              const float* eb, const float* inv_eb, const float* mask_db,
                                              float* qdk, float* qbk) {
    int u = blockIdx.x;
    int b = u & 31, pass = u >> 5;
    if (pass == 0)
        knrm_core<2, 4>(eq, inv_eq, mask_q, QL_, 0, b * QL_, ed, inv_ed, mask_d, DL_, b * DL_, b * DL_, qdk + b * 11);
    else
        knrm_core<2, 4>(eq, inv_eq, mask_q, QL_, 0, b * QL_, eb, inv_eb, mask_db, BL_, b * BL_, b * BL_, qbk + b * 11);
}

// B: kq/kd/kb over 8 cq instances: 8*32*10 = 2560 blocks
__global__ __launch_bounds__(256) void knrm_B(const float* eq, const float* inv_eq, const float* mask_q,
                                              const float* enc_d, const float* inv_encd, const float* mask_d,
                                              const float* enc_b, const float* inv_encb, const float* mask_db,
                                              const float* enc_dcq, const float* inv_encdcq, const float* mask_dcq,
                                              float* kq, float* kd, float* kb) {
    int u = blockIdx.x;
    int sub = u % 10;
    int ib = u / 10;
    int b = ib & 31, inst = ib >> 5;
    int dbase = b * (MN_ * ML_) + inst * ML_;
    if (sub == 0)
        knrm_core<4, 1>(eq, inv_eq, mask_q, QL_, 0, b * QL_, enc_dcq, inv_encdcq, mask_dcq, ML_, dbase, dbase,
                        kq + (size_t)(inst * BB + b) * 11);
    else if (sub == 1)
        knrm_core<4, 1>(enc_d, inv_encd, mask_d, DL_, 0, b * DL_, enc_dcq, inv_encdcq, mask_dcq, ML_, dbase, dbase,
                        kd + (size_t)(inst * BB + b) * 11);
    else
        knrm_core<4, 1>(enc_b, inv_encb, mask_db, BL_, (sub - 2) * 64, b * BL_, enc_dcq, inv_encdcq, mask_dcq, ML_,
                        dbase, dbase, kb + (size_t)(inst * BB + b) * 11);
}

// ---------------- final combine ----------------
__device__ inline float dot11(const float* w, const float* x) {
    float s = 0.f;
#pragma unroll
    for (int k = 0; k < 11; k++) s += w[k] * x[k];
    return s;
}

__global__ void final_kernel(const float* __restrict__ qdk, const float* __restrict__ qbk,
                             const float* __restrict__ kq, const float* __restrict__ kd,
                             const float* __restrict__ kb,
                             const float* qdW, const float* qdb, const float* qbW, const float* qbb,
                             const float* qcqW, const float* qcqb, const float* dcqW, const float* dcqb,
                             const float* bcqW, const float* bcqb, const float* expW, const float* expb,
                             const float* combW, const float* combb, float* __restrict__ out) {
    int b = threadIdx.x;
    if (b >= BB) return;
    float qd = tanhf(dot11(qdW, qdk + b * 11) + qdb[0]);
    float qb = tanhf(dot11(qbW, qbk + b * 11) + qbb[0]);
    float qcqd = 0.f, qcqb2 = 0.f;
    for (int i = 0; i < MN_; i++) {
        int base = (i * BB + b) * 11;
        float r  = tanhf(dot11(qcqW, kq + base) + qcqb[0]);
        float da = tanhf(dot11(dcqW, kd + base) + dcqb[0]);
        float ba = tanhf(dot11(bcqW, kb + base) + bcqb[0]);
        qcqd += r * da;
        qcqb2 += r * ba;
    }
    float qcq = expW[0] * qcqd + expW[1] * qcqb2 + expb[0];
    out[b] = tanhf(combW[0] * qd + combW[1] * qb + combW[2] * qcq + combb[0]);
}

extern "C" void kernel_launch(void* const* d_in, const int* in_sizes, int n_in,
                              void* d_out, int out_size, void* d_ws, size_t ws_size,
                              hipStream_t stream) {
    const int*   in_q    = (const int*)d_in[0];
    const int*   in_d    = (const int*)d_in[1];
    const int*   in_dcq  = (const int*)d_in[2];
    const int*   in_db   = (const int*)d_in[3];
    const float* mask_q  = (const float*)d_in[4];
    const float* mask_d  = (const float*)d_in[5];
    const float* mask_dcq= (const float*)d_in[6];
    const float* mask_db = (const float*)d_in[7];
    const float* emb     = (const float*)d_in[8];
    const float* Wq = (const float*)d_in[9];   const float* bq = (const float*)d_in[10];
    const float* Wk = (const float*)d_in[11];  const float* bk = (const float*)d_in[12];
    const float* Wv = (const float*)d_in[13];  const float* bv = (const float*)d_in[14];
    const float* Wo = (const float*)d_in[15];  const float* bo = (const float*)d_in[16];
    const float* tW = (const float*)d_in[17];  const float* tb = (const float*)d_in[18];
    const float* qdW = (const float*)d_in[19]; const float* qdb = (const float*)d_in[20];
    const float* qbW = (const float*)d_in[21]; const float* qbb = (const float*)d_in[22];
    const float* qcqW = (const float*)d_in[23];const float* qcqb = (const float*)d_in[24];
    const float* dcqW = (const float*)d_in[25];const float* dcqb = (const float*)d_in[26];
    const float* bcqW = (const float*)d_in[27];const float* bcqb = (const float*)d_in[28];
    const float* expW = (const float*)d_in[29];const float* expb = (const float*)d_in[30];
    const float* combW = (const float*)d_in[31];const float* combb = (const float*)d_in[32];
    float* out = (float*)d_out;

    float* ws = (float*)d_ws;
    size_t off = 0;
    auto alloc = [&](size_t n) { float* p = ws + off; off += n; return p; };
    float* eq      = alloc((size_t)BB * QL_ * DD);
    float* ed      = alloc((size_t)BB * DL_ * DD);
    float* eb      = alloc((size_t)BB * BL_ * DD);
    float* edcq    = alloc((size_t)BB * MN_ * ML_ * DD);
    float* enc_d   = alloc((size_t)BB * DL_ * DD);
    float* enc_b   = alloc((size_t)BB * BL_ * DD);
    float* enc_dcq = alloc((size_t)BB * MN_ * ML_ * DD);
    float* qbuf    = alloc((size_t)BB * BL_ * DD);
    float* kbuf    = alloc((size_t)BB * BL_ * DD);
    float* vbuf    = alloc((size_t)BB * BL_ * DD);
    float* ybuf    = alloc((size_t)BB * BL_ * DD);
    float* inv_eq     = alloc(BB * QL_);
    float* inv_ed     = alloc(BB * DL_);
    float* inv_eb     = alloc(BB * BL_);
    float* inv_encd   = alloc(BB * DL_);
    float* inv_encb   = alloc(BB * BL_);
    float* inv_encdcq = alloc(BB * MN_ * ML_);
    float* qdk = alloc(BB * 11);       // knrm outs: contiguous block, zeroed below
    float* qbk = alloc(BB * 11);
    float* kq  = alloc(MN_ * BB * 11);
    float* kd  = alloc(MN_ * BB * 11);
    float* kb  = alloc(MN_ * BB * 11);
    (void)ws_size; (void)in_sizes; (void)n_in; (void)out_size;

    // zero knrm accumulators (atomicAdd targets): 2*32*11 + 3*8*32*11 = 9152 floats
    zero_kernel<<<36, 256, 0, stream>>>(qdk, 9152);

    // embedding gathers
    gather_embed<<<(BB * QL_ * 32 + 255) / 256, 256, 0, stream>>>(in_q, emb, eq, BB * QL_);
    gather_embed<<<(BB * DL_ * 32 + 255) / 256, 256, 0, stream>>>(in_d, emb, ed, BB * DL_);
    gather_embed<<<(BB * BL_ * 32 + 255) / 256, 256, 0, stream>>>(in_db, emb, eb, BB * BL_);
    gather_embed<<<(BB * MN_ * ML_ * 32 + 255) / 256, 256, 0, stream>>>(in_dcq, emb, ybuf, BB * MN_ * ML_);
    linear_v2<<<BB * MN_ * ML_ / 32, 256, 0, stream>>>(ybuf, tW, tb, edcq, BB * MN_ * ML_);

    // MHA x3
    auto mha = [&](const float* x, float* outp, int L) {
        int R = BB * L;
        int gl = R / 32;
        linear_v2<<<gl, 256, 0, stream>>>(x, Wq, bq, qbuf, R);
        linear_v2<<<gl, 256, 0, stream>>>(x, Wk, bk, kbuf, R);
        linear_v2<<<gl, 256, 0, stream>>>(x, Wv, bv, vbuf, R);
        if (L == 64)       attn_v2<64, 1><<<BB * HH, 256, 0, stream>>>(qbuf, kbuf, vbuf, ybuf);
        else if (L == 128) attn_v2<128, 1><<<BB * HH, 256, 0, stream>>>(qbuf, kbuf, vbuf, ybuf);
        else               attn_v2<512, 2><<<BB * HH, 256, 0, stream>>>(qbuf, kbuf, vbuf, ybuf);
        linear_v2<<<gl, 256, 0, stream>>>(ybuf, Wo, bo, outp, R);
    };
    mha(edcq, enc_dcq, MN_ * ML_);  // L=128
    mha(ed, enc_d, DL_);            // L=64
    mha(eb, enc_b, BL_);            // L=512

    // row norms
    auto norms = [&](const float* x, float* inv, int R) {
        rownorm<<<(R * 64 + 255) / 256, 256, 0, stream>>>(x, inv, R);
    };
    norms(eq, inv_eq, BB * QL_);
    norms(ed, inv_ed, BB * DL_);
    norms(eb, inv_eb, BB * BL_);
    norms(enc_d, inv_encd, BB * DL_);
    norms(enc_b, inv_encb, BB * BL_);
    norms(enc_dcq, inv_encdcq, BB * MN_ * ML_);

    // KNRM: 2 launches
    knrm_A<<<64, 256, 0, stream>>>(eq, inv_eq, mask_q, ed, inv_ed, mask_d, eb, inv_eb, mask_db, qdk, qbk);
    knrm_B<<<2560, 256, 0, stream>>>(eq, inv_eq, mask_q, enc_d, inv_encd, mask_d, enc_b, inv_encb, mask_db,
                                     enc_dcq, inv_encdcq, mask_dcq, kq, kd, kb);

    // final combine
    final_kernel<<<1, 64, 0, stream>>>(qdk, qbk, kq, kd, kb,
                                       qdW, qdb, qbW, qbb, qcqW, qcqb, dcqW, dcqb,
                                       bcqW, bcqb, expW, expb, combW, combb, out);
}

// Round 3
// 478.613 us; speedup vs baseline: 10.4494x; 1.1939x over previous
//
#include <hip/hip_runtime.h>
#include <hip/hip_bf16.h>

// Model dims
#define BB 32
#define QL_ 20
#define DL_ 64
#define BL_ 512
#define MN_ 8
#define ML_ 16
#define DD 128
#define HH 8

typedef float f2 __attribute__((ext_vector_type(2)));

// ---------------- zero small region ----------------
__global__ void zero_kernel(float* __restrict__ p, int n) {
    int i = blockIdx.x * 256 + threadIdx.x;
    if (i < n) p[i] = 0.0f;
}

// ---------------- fused embedding gather + row inv-norm ----------------
// segments: [0,640) eq | [640,2688) ed | [2688,19072) eb | [19072,23168) dcq-tmp (no norm)
__global__ __launch_bounds__(256) void gather_all(
    const int* __restrict__ in_q, const int* __restrict__ in_d,
    const int* __restrict__ in_db, const int* __restrict__ in_dcq,
    const float* __restrict__ emb,
    float* __restrict__ eq, float* __restrict__ ed, float* __restrict__ eb, float* __restrict__ tmp,
    float* __restrict__ inv_eq, float* __restrict__ inv_ed, float* __restrict__ inv_eb) {
    int t = blockIdx.x * 256 + threadIdx.x;
    int r = t >> 5, c = t & 31;
    const int* idx; float* outp; float* invp; int lr;
    if (r < 640)        { idx = in_q;   outp = eq;  invp = inv_eq; lr = r; }
    else if (r < 2688)  { idx = in_d;   outp = ed;  invp = inv_ed; lr = r - 640; }
    else if (r < 19072) { idx = in_db;  outp = eb;  invp = inv_eb; lr = r - 2688; }
    else                { idx = in_dcq; outp = tmp; invp = nullptr; lr = r - 19072; }
    float4 val = ((const float4*)(emb + (size_t)idx[lr] * DD))[c];
    ((float4*)(outp + (size_t)lr * DD))[c] = val;
    float ss = val.x * val.x + val.y * val.y + val.z * val.z + val.w * val.w;
    ss += __shfl_xor(ss, 1, 64);
    ss += __shfl_xor(ss, 2, 64);
    ss += __shfl_xor(ss, 4, 64);
    ss += __shfl_xor(ss, 8, 64);
    ss += __shfl_xor(ss, 16, 64);
    if (c == 0 && invp) invp[lr] = 1.0f / fmaxf(sqrtf(ss), 1e-12f);
}

// ---------------- linear 128->128 + relu, 8x8 register tile ----------------
// block: 256 threads = 16 og (8 outs) x 16 rg (8 rows) -> 128 rows/block.
// W transposed in LDS (distinct-address b128 reads); x streamed from global.
__device__ __forceinline__ void linear_body(float* __restrict__ wT, float* __restrict__ bs,
                                            const float* __restrict__ in, const float* __restrict__ W,
                                            const float* __restrict__ bias, float* __restrict__ out,
                                            float* __restrict__ inv_out, int block) {
    int t = threadIdx.x;
    for (int i = t; i < DD * DD; i += 256) {
        int o = i >> 7, e = i & 127;
        wT[e * 132 + o] = W[i];               // global coalesced; LDS write conflicts one-time
    }
    if (t < 128) bs[t] = bias[t];
    __syncthreads();
    int og = t & 15, rg = t >> 4;
    int rowbase = block * 128 + rg * 8;
    f2 acc[8][4];
#pragma unroll
    for (int r = 0; r < 8; r++)
#pragma unroll
        for (int p = 0; p < 4; p++) acc[r][p] = f2{0.f, 0.f};
    for (int e4 = 0; e4 < 32; e4++) {
        float4 xv[8];
#pragma unroll
        for (int r = 0; r < 8; r++)
            xv[r] = *(const float4*)&in[(size_t)(rowbase + r) * DD + 4 * e4];
#pragma unroll
        for (int ee = 0; ee < 4; ee++) {
            int e = 4 * e4 + ee;
            float4 wa = *(const float4*)&wT[e * 132 + 8 * og];
            float4 wb = *(const float4*)&wT[e * 132 + 8 * og + 4];
            f2 w0 = {wa.x, wa.y}, w1 = {wa.z, wa.w}, w2 = {wb.x, wb.y}, w3 = {wb.z, wb.w};
#pragma unroll
            for (int r = 0; r < 8; r++) {
                float x = ((const float*)&xv[r])[ee];
                f2 x2 = {x, x};
                acc[r][0] = __builtin_elementwise_fma(x2, w0, acc[r][0]);
                acc[r][1] = __builtin_elementwise_fma(x2, w1, acc[r][1]);
                acc[r][2] = __builtin_elementwise_fma(x2, w2, acc[r][2]);
                acc[r][3] = __builtin_elementwise_fma(x2, w3, acc[r][3]);
            }
        }
    }
    float4 ba = *(const float4*)&bs[8 * og];
    float4 bbv = *(const float4*)&bs[8 * og + 4];
    float ss[8];
#pragma unroll
    for (int r = 0; r < 8; r++) {
        float o0 = fmaxf(acc[r][0].x + ba.x, 0.f);
        float o1 = fmaxf(acc[r][0].y + ba.y, 0.f);
        float o2 = fmaxf(acc[r][1].x + ba.z, 0.f);
        float o3 = fmaxf(acc[r][1].y + ba.w, 0.f);
        float o4 = fmaxf(acc[r][2].x + bbv.x, 0.f);
        float o5 = fmaxf(acc[r][2].y + bbv.y, 0.f);
        float o6 = fmaxf(acc[r][3].x + bbv.z, 0.f);
        float o7 = fmaxf(acc[r][3].y + bbv.w, 0.f);
        float4 s1 = {o0, o1, o2, o3}, s2 = {o4, o5, o6, o7};
        float* op = out + (size_t)(rowbase + r) * DD + 8 * og;
        *(float4*)op = s1;
        *(float4*)(op + 4) = s2;
        ss[r] = o0 * o0 + o1 * o1 + o2 * o2 + o3 * o3 + o4 * o4 + o5 * o5 + o6 * o6 + o7 * o7;
    }
    if (inv_out) {
#pragma unroll
        for (int r = 0; r < 8; r++) {
            ss[r] += __shfl_xor(ss[r], 1, 64);
            ss[r] += __shfl_xor(ss[r], 2, 64);
            ss[r] += __shfl_xor(ss[r], 4, 64);
            ss[r] += __shfl_xor(ss[r], 8, 64);
        }
#pragma unroll
        for (int r = 0; r < 8; r++)
            if (og == r) inv_out[rowbase + r] = 1.0f / fmaxf(sqrtf(ss[r]), 1e-12f);
    }
}

__global__ __launch_bounds__(256) void linear_v3(const float* __restrict__ in, const float* __restrict__ W,
                                                 const float* __restrict__ bias, float* __restrict__ out,
                                                 float* __restrict__ inv_out) {
    __shared__ float wT[DD * 132];
    __shared__ float bs[DD];
    linear_body(wT, bs, in, W, bias, out, inv_out, blockIdx.x);
}

__global__ __launch_bounds__(256) void qkv_v3(const float* __restrict__ in,
                                              const float* __restrict__ Wq, const float* __restrict__ bq,
                                              const float* __restrict__ Wk, const float* __restrict__ bk,
                                              const float* __restrict__ Wv, const float* __restrict__ bv,
                                              float* __restrict__ q, float* __restrict__ k, float* __restrict__ v,
                                              int gl) {
    __shared__ float wT[DD * 132];
    __shared__ float bs[DD];
    int sel = blockIdx.x / gl, blk = blockIdx.x % gl;
    const float* W = (sel == 0) ? Wq : (sel == 1) ? Wk : Wv;
    const float* B = (sel == 0) ? bq : (sel == 1) ? bk : bv;
    float* O = (sel == 0) ? q : (sel == 1) ? k : v;
    linear_body(wT, bs, in, W, B, O, nullptr, blk);
}

// ---------------- attention v4: e-split lanes, K/V in LDS, key-group partials ----------------
// lane = (ls:0..31, eh:0..1); thread owns NQ q-rows' 8-dim half; wave covers 32*NQ q-rows.
// waves split into KG key-groups; partials merged through LDS (softmax has no max-shift:
// plain exp sums, mathematically identical to reference softmax).
template <int L, int NQ>
__global__ __launch_bounds__(256) void attn_v4(const float* __restrict__ q,
                                               const float* __restrict__ k,
                                               const float* __restrict__ v,
                                               float* __restrict__ y) {
    constexpr int WQ = L / (32 * NQ);       // waves to cover q per key-group
    constexpr int KG = 4 / WQ;              // key groups
    constexpr int KPG = L / KG;             // keys per group
    constexpr int STAGE = L * 32;
    constexpr int PARTS = (KG - 1) * L * 20;
    constexpr int SM = (STAGE > PARTS) ? STAGE : PARTS;
    __shared__ float sm[SM];
    float* ks = sm;
    float* vs = sm + L * 16;
    int bh = blockIdx.x;
    int h = bh & 7, b = bh >> 3;
    int t = threadIdx.x;
    const size_t base = (size_t)b * L * DD + h * 16;
    for (int i = t; i < L * 4; i += 256) {
        int j = i >> 2, c = i & 3;
        *(float4*)&ks[j * 16 + 4 * c] = *(const float4*)&k[base + (size_t)j * DD + 4 * c];
        *(float4*)&vs[j * 16 + 4 * c] = *(const float4*)&v[base + (size_t)j * DD + 4 * c];
    }
    int w = t >> 6, lane = t & 63;
    int ls = lane & 31, eh = lane >> 5;
    int kg = w % KG, qw = w / KG;
    int qb = qw * 32 * NQ;
    f2 qv[NQ][4];
#pragma unroll
    for (int n = 0; n < NQ; n++) {
        int qr = qb + ls + 32 * n;
        const float* qp = q + base + (size_t)qr * DD + eh * 8;
        float4 a = *(const float4*)qp;
        float4 b4 = *(const float4*)(qp + 4);
        qv[n][0] = f2{a.x, a.y};  qv[n][1] = f2{a.z, a.w};
        qv[n][2] = f2{b4.x, b4.y}; qv[n][3] = f2{b4.z, b4.w};
    }
    f2 acc[NQ][4];
    float l[NQ];
#pragma unroll
    for (int n = 0; n < NQ; n++) {
#pragma unroll
        for (int m = 0; m < 4; m++) acc[n][m] = f2{0.f, 0.f};
        l[n] = 0.f;
    }
    __syncthreads();
    for (int j = kg * KPG; j < (kg + 1) * KPG; j++) {
        float4 ka = *(const float4*)&ks[j * 16 + eh * 8];
        float4 kb2 = *(const float4*)&ks[j * 16 + eh * 8 + 4];
        float4 va = *(const float4*)&vs[j * 16 + eh * 8];
        float4 vb2 = *(const float4*)&vs[j * 16 + eh * 8 + 4];
        f2 kk0 = {ka.x, ka.y}, kk1 = {ka.z, ka.w}, kk2 = {kb2.x, kb2.y}, kk3 = {kb2.z, kb2.w};
        f2 vv0 = {va.x, va.y}, vv1 = {va.z, va.w}, vv2 = {vb2.x, vb2.y}, vv3 = {vb2.z, vb2.w};
#pragma unroll
        for (int n = 0; n < NQ; n++) {
            f2 d2 = qv[n][0] * kk0;
            d2 = __builtin_elementwise_fma(qv[n][1], kk1, d2);
            d2 = __builtin_elementwise_fma(qv[n][2], kk2, d2);
            d2 = __builtin_elementwise_fma(qv[n][3], kk3, d2);
            float sh = d2.x + d2.y;
            float s = sh + __shfl_xor(sh, 32, 64);
            float p = __expf(s * 0.25f);
            l[n] += p;
            f2 p2 = {p, p};
            acc[n][0] = __builtin_elementwise_fma(p2, vv0, acc[n][0]);
            acc[n][1] = __builtin_elementwise_fma(p2, vv1, acc[n][1]);
            acc[n][2] = __builtin_elementwise_fma(p2, vv2, acc[n][2]);
            acc[n][3] = __builtin_elementwise_fma(p2, vv3, acc[n][3]);
        }
    }
    __syncthreads();   // done reading ks/vs; reuse sm for partials
    if (kg > 0) {
#pragma unroll
        for (int n = 0; n < NQ; n++) {
            int qr = qb + ls + 32 * n;
            float* pp = &sm[((kg - 1) * L + qr) * 20 + eh * 10];
            *(f2*)&pp[0] = acc[n][0];
            *(f2*)&pp[2] = acc[n][1];
            *(f2*)&pp[4] = acc[n][2];
            *(f2*)&pp[6] = acc[n][3];
            pp[8] = l[n];
        }
    }
    __syncthreads();
    if (kg == 0) {
#pragma unroll
        for (int n = 0; n < NQ; n++) {
            int qr = qb + ls + 32 * n;
            f2 a0 = acc[n][0], a1 = acc[n][1], a2 = acc[n][2], a3 = acc[n][3];
            float lt = l[n];
#pragma unroll
            for (int g = 1; g < KG; g++) {
                const float* pp = &sm[((g - 1) * L + qr) * 20 + eh * 10];
                a0 += *(const f2*)&pp[0];
                a1 += *(const f2*)&pp[2];
                a2 += *(const f2*)&pp[4];
                a3 += *(const f2*)&pp[6];
                lt += pp[8];
            }
            float inv = 1.0f / lt;
            float4 o1 = {a0.x * inv, a0.y * inv, a1.x * inv, a1.y * inv};
            float4 o2 = {a2.x * inv, a2.y * inv, a3.x * inv, a3.y * inv};
            float* yp = y + base + (size_t)qr * DD + eh * 8;
            *(float4*)yp = o1;
            *(float4*)(yp + 4) = o2;
        }
    }
}

// ---------------- KNRM core (smem passed in) ----------------
template <int QPT, int DPT>
__device__ void knrm_core(float* __restrict__ sm,
                          const float* __restrict__ Q, const float* __restrict__ invQ,
                          const float* __restrict__ mq, int QL, int q0, int qbase,
                          const float* __restrict__ D, const float* __restrict__ invD,
                          const float* __restrict__ md, int DL, int dbase, int mdbase,
                          float* __restrict__ out) {
    constexpr int QT = QPT * 16, DT = DPT * 16;
    float* qtile = sm;                    // QT*132
    float* dtile = qtile + QT * 132;      // DT*132
    float* mdv = dtile + DT * 132;        // DT
    float* red = mdv + DT;                // 4*16*QPT*11
    float* outred = red + 4 * 16 * QPT * 11;  // 11
    const float MUc[11] = {1.0f, 0.9f, 0.7f, 0.5f, 0.3f, 0.1f, -0.1f, -0.3f, -0.5f, -0.7f, -0.9f};
    const float NC[11]  = {-500000.0f, -50.f, -50.f, -50.f, -50.f, -50.f, -50.f, -50.f, -50.f, -50.f, -50.f};
    int t = threadIdx.x;
    int tq = t & 15, td = t >> 4;
    if (t < 11) outred[t] = 0.f;
    for (int i = t; i < QT * 32; i += 256) {
        int r = i >> 5, c = i & 31;
        int qrow = q0 + r;
        float4 val = make_float4(0.f, 0.f, 0.f, 0.f);
        if (qrow < QL) {
            float s = invQ[qbase + qrow];
            float4 g = *(const float4*)(Q + (size_t)(qbase + qrow) * DD + 4 * c);
            val = make_float4(g.x * s, g.y * s, g.z * s, g.w * s);
        }
        *(float4*)&qtile[r * 132 + 4 * c] = val;
    }
    float ps[QPT][11];
#pragma unroll
    for (int i = 0; i < QPT; i++)
#pragma unroll
        for (int kk = 0; kk < 11; kk++) ps[i][kk] = 0.f;

    for (int d0 = 0; d0 < DL; d0 += DT) {
        for (int i = t; i < DT * 32; i += 256) {
            int r = i >> 5, c = i & 31;
            int drow = d0 + r;
            float4 val = make_float4(0.f, 0.f, 0.f, 0.f);
            if (drow < DL) {
                float s = invD[dbase + drow];
                float4 g = *(const float4*)(D + (size_t)(dbase + drow) * DD + 4 * c);
                val = make_float4(g.x * s, g.y * s, g.z * s, g.w * s);
            }
            *(float4*)&dtile[r * 132 + 4 * c] = val;
        }
        if (t < DT) mdv[t] = (d0 + t < DL) ? md[mdbase + d0 + t] : 0.f;
        __syncthreads();
        float dot[QPT][DPT];
#pragma unroll
        for (int i = 0; i < QPT; i++)
#pragma unroll
            for (int j = 0; j < DPT; j++) dot[i][j] = 0.f;
#pragma unroll 2
        for (int e4 = 0; e4 < 32; e4++) {
            float4 qv[QPT], dv[DPT];
#pragma unroll
            for (int i = 0; i < QPT; i++) qv[i] = *(const float4*)&qtile[(tq + 16 * i) * 132 + 4 * e4];
#pragma unroll
            for (int j = 0; j < DPT; j++) dv[j] = *(const float4*)&dtile[(td + 16 * j) * 132 + 4 * e4];
#pragma unroll
            for (int i = 0; i < QPT; i++)
#pragma unroll
                for (int j = 0; j < DPT; j++)
                    dot[i][j] += qv[i].x * dv[j].x + qv[i].y * dv[j].y + qv[i].z * dv[j].z + qv[i].w * dv[j].w;
        }
#pragma unroll
        for (int j = 0; j < DPT; j++) {
            float m = mdv[td + 16 * j];
#pragma unroll
            for (int i = 0; i < QPT; i++) {
                float sim = dot[i][j];
#pragma unroll
                for (int kk = 0; kk < 11; kk++) {
                    float df = sim - MUc[kk];
                    ps[i][kk] = fmaf(__expf(df * df * NC[kk]), m, ps[i][kk]);
                }
            }
        }
        __syncthreads();
    }
#pragma unroll
    for (int i = 0; i < QPT; i++)
#pragma unroll
        for (int kk = 0; kk < 11; kk++) {
            ps[i][kk] += __shfl_xor(ps[i][kk], 16, 64);
            ps[i][kk] += __shfl_xor(ps[i][kk], 32, 64);
        }
    int w = t >> 6;
    if ((t & 63) < 16) {
#pragma unroll
        for (int i = 0; i < QPT; i++)
#pragma unroll
            for (int kk = 0; kk < 11; kk++) red[(w * 16 + tq) * (QPT * 11) + i * 11 + kk] = ps[i][kk];
    }
    __syncthreads();
    for (int i = t; i < 16 * QPT * 11; i += 256) {
        int tq2 = i / (QPT * 11);
        int rem = i - tq2 * (QPT * 11);
        int qi = rem / 11, kk = rem - qi * 11;
        float s = red[(0 * 16 + tq2) * (QPT * 11) + qi * 11 + kk] + red[(1 * 16 + tq2) * (QPT * 11) + qi * 11 + kk]
                + red[(2 * 16 + tq2) * (QPT * 11) + qi * 11 + kk] + red[(3 * 16 + tq2) * (QPT * 11) + qi * 11 + kk];
        int qrow = q0 + tq2 + 16 * qi;
        if (qrow < QL) {
            float lps = logf(fmaxf(s, 1e-10f)) * mq[qbase + qrow] * 0.01f;
            atomicAdd(&outred[kk], lps);
        }
    }
    __syncthreads();
    if (t < 11) atomicAdd(&out[t], outred[t]);
}

// single fused KNRM launch: blocks [0,32) qd | [32,64) qb | [64,2624) kq/kd/kb
__global__ __launch_bounds__(256) void knrm_all(
    const float* __restrict__ eq, const float* __restrict__ inv_eq, const float* __restrict__ mask_q,
    const float* __restrict__ ed, const float* __restrict__ inv_ed, const float* __restrict__ mask_d,
    const float* __restrict__ eb, const float* __restrict__ inv_eb, const float* __restrict__ mask_db,
    const float* __restrict__ enc_d, const float* __restrict__ inv_encd,
    const float* __restrict__ enc_b, const float* __restrict__ inv_encb,
    const float* __restrict__ enc_dcq, const float* __restrict__ inv_encdcq, const float* __restrict__ mask_dcq,
    float* __restrict__ qdk, float* __restrict__ qbk,
    float* __restrict__ kq, float* __restrict__ kd, float* __restrict__ kb) {
    __shared__ float sm[14155];
    int blk = blockIdx.x;
    if (blk < 32) {
        int b = blk;
        knrm_core<2, 4>(sm, eq, inv_eq, mask_q, QL_, 0, b * QL_, ed, inv_ed, mask_d, DL_, b * DL_, b * DL_, qdk + b * 11);
    } else if (blk < 64) {
        int b = blk - 32;
        knrm_core<2, 4>(sm, eq, inv_eq, mask_q, QL_, 0, b * QL_, eb, inv_eb, mask_db, BL_, b * BL_, b * BL_, qbk + b * 11);
    } else {
        int u = blk - 64;
        int sub = u % 10;
        int ib = u / 10;
        int b = ib & 31, inst = ib >> 5;
        int dbase = b * (MN_ * ML_) + inst * ML_;
        if (sub == 0)
            knrm_core<4, 1>(sm, eq, inv_eq, mask_q, QL_, 0, b * QL_, enc_dcq, inv_encdcq, mask_dcq, ML_, dbase, dbase,
                            kq + (size_t)(inst * BB + b) * 11);
        else if (sub == 1)
            knrm_core<4, 1>(sm, enc_d, inv_encd, mask_d, DL_, 0, b * DL_, enc_dcq, inv_encdcq, mask_dcq, ML_, dbase, dbase,
                            kd + (size_t)(inst * BB + b) * 11);
        else
            knrm_core<4, 1>(sm, enc_b, inv_encb, mask_db, BL_, (sub - 2) * 64, b * BL_, enc_dcq, inv_encdcq, mask_dcq, ML_,
                            dbase, dbase, kb + (size_t)(inst * BB + b) * 11);
    }
}

// ---------------- final combine ----------------
__device__ inline float dot11(const float* w, const float* x) {
    float s = 0.f;
#pragma unroll
    for (int k = 0; k < 11; k++) s += w[k] * x[k];
    return s;
}

__global__ void final_kernel(const float* __restrict__ qdk, const float* __restrict__ qbk,
                             const float* __restrict__ kq, const float* __restrict__ kd,
                             const float* __restrict__ kb,
                             const float* qdW, const float* qdb, const float* qbW, const float* qbb,
                             const float* qcqW, const float* qcqb, const float* dcqW, const float* dcqb,
                             const float* bcqW, const float* bcqb, const float* expW, const float* expb,
                             const float* combW, const float* combb, float* __restrict__ out) {
    int b = threadIdx.x;
    if (b >= BB) return;
    float qd = tanhf(dot11(qdW, qdk + b * 11) + qdb[0]);
    float qb = tanhf(dot11(qbW, qbk + b * 11) + qbb[0]);
    float qcqd = 0.f, qcqb2 = 0.f;
    for (int i = 0; i < MN_; i++) {
        int base = (i * BB + b) * 11;
        float r  = tanhf(dot11(qcqW, kq + base) + qcqb[0]);
        float da = tanhf(dot11(dcqW, kd + base) + dcqb[0]);
        float ba = tanhf(dot11(bcqW, kb + base) + bcqb[0]);
        qcqd += r * da;
        qcqb2 += r * ba;
    }
    float qcq = expW[0] * qcqd + expW[1] * qcqb2 + expb[0];
    out[b] = tanhf(combW[0] * qd + combW[1] * qb + combW[2] * qcq + combb[0]);
}

extern "C" void kernel_launch(void* const* d_in, const int* in_sizes, int n_in,
                              void* d_out, int out_size, void* d_ws, size_t ws_size,
                              hipStream_t stream) {
    const int*   in_q    = (const int*)d_in[0];
    const int*   in_d    = (const int*)d_in[1];
    const int*   in_dcq  = (const int*)d_in[2];
    const int*   in_db   = (const int*)d_in[3];
    const float* mask_q  = (const float*)d_in[4];
    const float* mask_d  = (const float*)d_in[5];
    const float* mask_dcq= (const float*)d_in[6];
    const float* mask_db = (const float*)d_in[7];
    const float* emb     = (const float*)d_in[8];
    const float* Wq = (const float*)d_in[9];   const float* bq = (const float*)d_in[10];
    const float* Wk = (const float*)d_in[11];  const float* bk = (const float*)d_in[12];
    const float* Wv = (const float*)d_in[13];  const float* bv = (const float*)d_in[14];
    const float* Wo = (const float*)d_in[15];  const float* bo = (const float*)d_in[16];
    const float* tW = (const float*)d_in[17];  const float* tb = (const float*)d_in[18];
    const float* qdW = (const float*)d_in[19]; const float* qdb = (const float*)d_in[20];
    const float* qbW = (const float*)d_in[21]; const float* qbb = (const float*)d_in[22];
    const float* qcqW = (const float*)d_in[23];const float* qcqb = (const float*)d_in[24];
    const float* dcqW = (const float*)d_in[25];const float* dcqb = (const float*)d_in[26];
    const float* bcqW = (const float*)d_in[27];const float* bcqb = (const float*)d_in[28];
    const float* expW = (const float*)d_in[29];const float* expb = (const float*)d_in[30];
    const float* combW = (const float*)d_in[31];const float* combb = (const float*)d_in[32];
    float* out = (float*)d_out;

    float* ws = (float*)d_ws;
    size_t off = 0;
    auto alloc = [&](size_t n) { float* p = ws + off; off += n; return p; };
    float* eq      = alloc((size_t)BB * QL_ * DD);
    float* ed      = alloc((size_t)BB * DL_ * DD);
    float* eb      = alloc((size_t)BB * BL_ * DD);
    float* edcq    = alloc((size_t)BB * MN_ * ML_ * DD);
    float* enc_d   = alloc((size_t)BB * DL_ * DD);
    float* enc_b   = alloc((size_t)BB * BL_ * DD);
    float* enc_dcq = alloc((size_t)BB * MN_ * ML_ * DD);
    float* qbuf    = alloc((size_t)BB * BL_ * DD);
    float* kbuf    = alloc((size_t)BB * BL_ * DD);
    float* vbuf    = alloc((size_t)BB * BL_ * DD);
    float* ybuf    = alloc((size_t)BB * BL_ * DD);
    float* inv_eq     = alloc(BB * QL_);
    float* inv_ed     = alloc(BB * DL_);
    float* inv_eb     = alloc(BB * BL_);
    float* inv_encd   = alloc(BB * DL_);
    float* inv_encb   = alloc(BB * BL_);
    float* inv_encdcq = alloc(BB * MN_ * ML_);
    float* qdk = alloc(BB * 11);       // knrm outs: contiguous block, zeroed below
    float* qbk = alloc(BB * 11);
    float* kq  = alloc(MN_ * BB * 11);
    float* kd  = alloc(MN_ * BB * 11);
    float* kb  = alloc(MN_ * BB * 11);
    (void)ws_size; (void)in_sizes; (void)n_in; (void)out_size;

    // zero knrm atomic accumulators: 2*32*11 + 3*8*32*11 = 9152 floats
    zero_kernel<<<36, 256, 0, stream>>>(qdk, 9152);

    // fused gathers + eq/ed/eb norms (dcq tokens -> ybuf tmp)
    gather_all<<<2896, 256, 0, stream>>>(in_q, in_d, in_db, in_dcq, emb,
                                         eq, ed, eb, ybuf, inv_eq, inv_ed, inv_eb);
    // t-projection
    linear_v3<<<BB * MN_ * ML_ / 128, 256, 0, stream>>>(ybuf, tW, tb, edcq, nullptr);

    // MHA x3 (out-proj fuses the row-norm epilogue)
    auto mha = [&](const float* x, float* outp, float* invp, int L) {
        int R = BB * L;
        int gl = R / 128;
        qkv_v3<<<3 * gl, 256, 0, stream>>>(x, Wq, bq, Wk, bk, Wv, bv, qbuf, kbuf, vbuf, gl);
        if (L == 64)       attn_v4<64, 2><<<BB * HH, 256, 0, stream>>>(qbuf, kbuf, vbuf, ybuf);
        else if (L == 128) attn_v4<128, 4><<<BB * HH, 256, 0, stream>>>(qbuf, kbuf, vbuf, ybuf);
        else               attn_v4<512, 8><<<BB * HH, 256, 0, stream>>>(qbuf, kbuf, vbuf, ybuf);
        linear_v3<<<gl, 256, 0, stream>>>(ybuf, Wo, bo, outp, invp);
    };
    mha(edcq, enc_dcq, inv_encdcq, MN_ * ML_);  // L=128
    mha(ed, enc_d, inv_encd, DL_);              // L=64
    mha(eb, enc_b, inv_encb, BL_);              // L=512

    // KNRM: one launch
    knrm_all<<<2624, 256, 0, stream>>>(eq, inv_eq, mask_q, ed, inv_ed, mask_d, eb, inv_eb, mask_db,
                                       enc_d, inv_encd, enc_b, inv_encb, enc_dcq, inv_encdcq, mask_dcq,
                                       qdk, qbk, kq, kd, kb);

    // final combine
    final_kernel<<<1, 64, 0, stream>>>(qdk, qbk, kq, kd, kb,
                                       qdW, qdb, qbW, qbb, qcqW, qcqb, dcqW, dcqb,
                                       bcqW, bcqb, expW, expb, combW, combb, out);
}

// Round 4
// 391.920 us; speedup vs baseline: 12.7608x; 1.2212x over previous
//
#include <hip/hip_runtime.h>
#include <hip/hip_bf16.h>

// Model dims
#define BB 32
#define QL_ 20
#define DL_ 64
#define BL_ 512
#define MN_ 8
#define ML_ 16
#define DD 128
#define HH 8

// concatenated row-space for MHA: [dcq | d | b]; eq appended for gather only
#define ROWS_DCQ 4096
#define ROWS_D   2048
#define ROWS_B   16384
#define R_ALL    22528
#define ROWS_EQ  640
#define R_GATHER 23168

typedef float f2 __attribute__((ext_vector_type(2)));

// ---------------- fused gather (+norms) + zero of knrm accumulators ----------------
__global__ __launch_bounds__(256) void gather_all(
    const int* __restrict__ in_q, const int* __restrict__ in_d,
    const int* __restrict__ in_dcq, const int* __restrict__ in_db,
    const float* __restrict__ emb, float* __restrict__ x_all, float* __restrict__ ytmp,
    float* __restrict__ inv_eq, float* __restrict__ inv_ed, float* __restrict__ inv_eb,
    float* __restrict__ zero_p, int nzero) {
    int blk = blockIdx.x;
    if (blk >= 2896) {                      // zero tail
        int i = (blk - 2896) * 256 + threadIdx.x;
        if (i < nzero) zero_p[i] = 0.f;
        return;
    }
    int t = blk * 256 + threadIdx.x;
    int r = t >> 5, c = t & 31;
    const int* idx; float* outp; float* invp; int lr;
    if (r < ROWS_DCQ)              { idx = in_dcq; outp = ytmp + (size_t)r * DD;  invp = nullptr; lr = r; }
    else if (r < ROWS_DCQ + ROWS_D){ idx = in_d;   outp = x_all + (size_t)r * DD; invp = inv_ed;  lr = r - ROWS_DCQ; }
    else if (r < R_ALL)            { idx = in_db;  outp = x_all + (size_t)r * DD; invp = inv_eb;  lr = r - (ROWS_DCQ + ROWS_D); }
    else                           { idx = in_q;   outp = x_all + (size_t)r * DD; invp = inv_eq;  lr = r - R_ALL; }
    float4 val = ((const float4*)(emb + (size_t)idx[lr] * DD))[c];
    ((float4*)outp)[c] = val;
    float ss = val.x * val.x + val.y * val.y + val.z * val.z + val.w * val.w;
    ss += __shfl_xor(ss, 1, 64);
    ss += __shfl_xor(ss, 2, 64);
    ss += __shfl_xor(ss, 4, 64);
    ss += __shfl_xor(ss, 8, 64);
    ss += __shfl_xor(ss, 16, 64);
    if (c == 0 && invp) invp[lr] = 1.0f / fmaxf(sqrtf(ss), 1e-12f);
}

// ---------------- linear 128->128 + relu, 8x8 register tile (x from global/L2) -------
__device__ __forceinline__ void linear_body(float* __restrict__ wT, float* __restrict__ bs,
                                            const float* __restrict__ in, const float* __restrict__ W,
                                            const float* __restrict__ bias, float* __restrict__ out,
                                            float* __restrict__ inv_out, int block) {
    int t = threadIdx.x;
    for (int i = t; i < DD * DD; i += 256) {
        int o = i >> 7, e = i & 127;
        wT[e * 132 + o] = W[i];
    }
    if (t < 128) bs[t] = bias[t];
    __syncthreads();
    int og = t & 15, rg = t >> 4;
    int rowbase = block * 128 + rg * 8;
    f2 acc[8][4];
#pragma unroll
    for (int r = 0; r < 8; r++)
#pragma unroll
        for (int p = 0; p < 4; p++) acc[r][p] = f2{0.f, 0.f};
    for (int e4 = 0; e4 < 32; e4++) {
        float4 xv[8];
#pragma unroll
        for (int r = 0; r < 8; r++)
            xv[r] = *(const float4*)&in[(size_t)(rowbase + r) * DD + 4 * e4];
#pragma unroll
        for (int ee = 0; ee < 4; ee++) {
            int e = 4 * e4 + ee;
            float4 wa = *(const float4*)&wT[e * 132 + 8 * og];
            float4 wb = *(const float4*)&wT[e * 132 + 8 * og + 4];
            f2 w0 = {wa.x, wa.y}, w1 = {wa.z, wa.w}, w2 = {wb.x, wb.y}, w3 = {wb.z, wb.w};
#pragma unroll
            for (int r = 0; r < 8; r++) {
                float x = ((const float*)&xv[r])[ee];
                f2 x2 = {x, x};
                acc[r][0] = __builtin_elementwise_fma(x2, w0, acc[r][0]);
                acc[r][1] = __builtin_elementwise_fma(x2, w1, acc[r][1]);
                acc[r][2] = __builtin_elementwise_fma(x2, w2, acc[r][2]);
                acc[r][3] = __builtin_elementwise_fma(x2, w3, acc[r][3]);
            }
        }
    }
    float4 ba = *(const float4*)&bs[8 * og];
    float4 bbv = *(const float4*)&bs[8 * og + 4];
    float ss[8];
#pragma unroll
    for (int r = 0; r < 8; r++) {
        float o0 = fmaxf(acc[r][0].x + ba.x, 0.f);
        float o1 = fmaxf(acc[r][0].y + ba.y, 0.f);
        float o2 = fmaxf(acc[r][1].x + ba.z, 0.f);
        float o3 = fmaxf(acc[r][1].y + ba.w, 0.f);
        float o4 = fmaxf(acc[r][2].x + bbv.x, 0.f);
        float o5 = fmaxf(acc[r][2].y + bbv.y, 0.f);
        float o6 = fmaxf(acc[r][3].x + bbv.z, 0.f);
        float o7 = fmaxf(acc[r][3].y + bbv.w, 0.f);
        float4 s1 = {o0, o1, o2, o3}, s2 = {o4, o5, o6, o7};
        float* op = out + (size_t)(rowbase + r) * DD + 8 * og;
        *(float4*)op = s1;
        *(float4*)(op + 4) = s2;
        ss[r] = o0 * o0 + o1 * o1 + o2 * o2 + o3 * o3 + o4 * o4 + o5 * o5 + o6 * o6 + o7 * o7;
    }
    if (inv_out) {
#pragma unroll
        for (int r = 0; r < 8; r++) {
            ss[r] += __shfl_xor(ss[r], 1, 64);
            ss[r] += __shfl_xor(ss[r], 2, 64);
            ss[r] += __shfl_xor(ss[r], 4, 64);
            ss[r] += __shfl_xor(ss[r], 8, 64);
        }
#pragma unroll
        for (int r = 0; r < 8; r++)
            if (og == r) inv_out[rowbase + r] = 1.0f / fmaxf(sqrtf(ss[r]), 1e-12f);
    }
}

__global__ __launch_bounds__(256) void lin_kernel(const float* __restrict__ in, const float* __restrict__ W,
                                                  const float* __restrict__ bias, float* __restrict__ out,
                                                  float* __restrict__ inv_out) {
    __shared__ float wT[DD * 132];
    __shared__ float bs[DD];
    linear_body(wT, bs, in, W, bias, out, inv_out, blockIdx.x);
}

__global__ __launch_bounds__(256) void qkv_all(const float* __restrict__ x,
                                               const float* __restrict__ Wq, const float* __restrict__ bq,
                                               const float* __restrict__ Wk, const float* __restrict__ bk,
                                               const float* __restrict__ Wv, const float* __restrict__ bv,
                                               float* __restrict__ q, float* __restrict__ k, float* __restrict__ v) {
    __shared__ float wT[DD * 132];
    __shared__ float bs[DD];
    int sel = blockIdx.x / 176, blk = blockIdx.x % 176;
    const float* W = (sel == 0) ? Wq : (sel == 1) ? Wk : Wv;
    const float* B = (sel == 0) ? bq : (sel == 1) ? bk : bv;
    float* O = (sel == 0) ? q : (sel == 1) ? k : v;
    linear_body(wT, bs, x, W, B, O, nullptr, blk);
}

// ---------------- attention: e-split lanes, 16 waves, key-group partials ----------------
// no softmax max-shift: exp-sum form is algebraically identical; scores are tiny relu-dots/4.
template <int L, int NQ>
__device__ __forceinline__ void attn_body(float* __restrict__ sm, const float* __restrict__ q,
                                          const float* __restrict__ k, const float* __restrict__ v,
                                          float* __restrict__ y, int bh) {
    constexpr int WAVES = 16;
    constexpr int WQ = L / (32 * NQ);
    constexpr int KG = WAVES / WQ;
    constexpr int KPG = L / KG;
    float* ks = sm;
    float* vs = sm + L * 16;
    int h = bh & 7, b = bh >> 3;
    int t = threadIdx.x;
    const size_t base = (size_t)b * L * DD + h * 16;
    for (int i = t; i < L * 4; i += 1024) {
        int j = i >> 2, c = i & 3;
        *(float4*)&ks[j * 16 + 4 * c] = *(const float4*)&k[base + (size_t)j * DD + 4 * c];
        *(float4*)&vs[j * 16 + 4 * c] = *(const float4*)&v[base + (size_t)j * DD + 4 * c];
    }
    int w = t >> 6, lane = t & 63;
    int ls = lane & 31, eh = lane >> 5;
    int kg = w % KG, qw = w / KG;
    int qb2 = qw * 32 * NQ;
    f2 qv[NQ][4];
#pragma unroll
    for (int n = 0; n < NQ; n++) {
        int qr = qb2 + ls + 32 * n;
        const float* qp = q + base + (size_t)qr * DD + eh * 8;
        float4 a = *(const float4*)qp;
        float4 b4 = *(const float4*)(qp + 4);
        qv[n][0] = f2{a.x, a.y};   qv[n][1] = f2{a.z, a.w};
        qv[n][2] = f2{b4.x, b4.y}; qv[n][3] = f2{b4.z, b4.w};
    }
    f2 acc[NQ][4];
    float l[NQ];
#pragma unroll
    for (int n = 0; n < NQ; n++) {
#pragma unroll
        for (int m = 0; m < 4; m++) acc[n][m] = f2{0.f, 0.f};
        l[n] = 0.f;
    }
    __syncthreads();
    for (int j = kg * KPG; j < (kg + 1) * KPG; j++) {
        float4 ka = *(const float4*)&ks[j * 16 + eh * 8];
        float4 kb2 = *(const float4*)&ks[j * 16 + eh * 8 + 4];
        float4 va = *(const float4*)&vs[j * 16 + eh * 8];
        float4 vb2 = *(const float4*)&vs[j * 16 + eh * 8 + 4];
        f2 kk0 = {ka.x, ka.y}, kk1 = {ka.z, ka.w}, kk2 = {kb2.x, kb2.y}, kk3 = {kb2.z, kb2.w};
        f2 vv0 = {va.x, va.y}, vv1 = {va.z, va.w}, vv2 = {vb2.x, vb2.y}, vv3 = {vb2.z, vb2.w};
#pragma unroll
        for (int n = 0; n < NQ; n++) {
            f2 d2 = qv[n][0] * kk0;
            d2 = __builtin_elementwise_fma(qv[n][1], kk1, d2);
            d2 = __builtin_elementwise_fma(qv[n][2], kk2, d2);
            d2 = __builtin_elementwise_fma(qv[n][3], kk3, d2);
            float sh = d2.x + d2.y;
            float s = sh + __shfl_xor(sh, 32, 64);
            float p = __expf(s * 0.25f);
            l[n] += p;
            f2 p2 = {p, p};
            acc[n][0] = __builtin_elementwise_fma(p2, vv0, acc[n][0]);
            acc[n][1] = __builtin_elementwise_fma(p2, vv1, acc[n][1]);
            acc[n][2] = __builtin_elementwise_fma(p2, vv2, acc[n][2]);
            acc[n][3] = __builtin_elementwise_fma(p2, vv3, acc[n][3]);
        }
    }
    __syncthreads();   // done with ks/vs; reuse sm for partials
    if (kg > 0) {
#pragma unroll
        for (int n = 0; n < NQ; n++) {
            int qr = qb2 + ls + 32 * n;
            float* pp = &sm[((kg - 1) * L + qr) * 20 + eh * 10];
            *(f2*)&pp[0] = acc[n][0];
            *(f2*)&pp[2] = acc[n][1];
            *(f2*)&pp[4] = acc[n][2];
            *(f2*)&pp[6] = acc[n][3];
            pp[8] = l[n];
        }
    }
    __syncthreads();
    if (kg == 0) {
#pragma unroll
        for (int n = 0; n < NQ; n++) {
            int qr = qb2 + ls + 32 * n;
            f2 a0 = acc[n][0], a1 = acc[n][1], a2 = acc[n][2], a3 = acc[n][3];
            float lt = l[n];
#pragma unroll
            for (int g = 1; g < KG; g++) {
                const float* pp = &sm[((g - 1) * L + qr) * 20 + eh * 10];
                a0 += *(const f2*)&pp[0];
                a1 += *(const f2*)&pp[2];
                a2 += *(const f2*)&pp[4];
                a3 += *(const f2*)&pp[6];
                lt += pp[8];
            }
            float inv = 1.0f / lt;
            float4 o1 = {a0.x * inv, a0.y * inv, a1.x * inv, a1.y * inv};
            float4 o2 = {a2.x * inv, a2.y * inv, a3.x * inv, a3.y * inv};
            float* yp = y + base + (size_t)qr * DD + eh * 8;
            *(float4*)yp = o1;
            *(float4*)(yp + 4) = o2;
        }
    }
}

__global__ __launch_bounds__(1024) void attn_all(const float* __restrict__ qb_, const float* __restrict__ kb_,
                                                 const float* __restrict__ vb_, float* __restrict__ yb_) {
    __shared__ float sm[16384];            // 64 KB: stage (L*32 max) and partials both fit
    int blk = blockIdx.x;
    if (blk < 256) {
        const size_t off = (size_t)(ROWS_DCQ + ROWS_D) * DD;
        attn_body<512, 2>(sm, qb_ + off, kb_ + off, vb_ + off, yb_ + off, blk);
    } else if (blk < 512) {
        attn_body<128, 1>(sm, qb_, kb_, vb_, yb_, blk - 256);
    } else {
        const size_t off = (size_t)ROWS_DCQ * DD;
        attn_body<64, 1>(sm, qb_ + off, kb_ + off, vb_ + off, yb_ + off, blk - 512);
    }
}

// ---------------- KNRM core: register-tiled sims + gaussian kernels ----------------
template <int QPT, int DPT>
__device__ void knrm_core(float* __restrict__ sm,
                          const float* __restrict__ Q, const float* __restrict__ invQ,
                          const float* __restrict__ mq, int QL, int q0, int qbase,
                          const float* __restrict__ D, const float* __restrict__ invD,
                          const float* __restrict__ md, int DL, int dbase, int mdbase,
                          float* __restrict__ out) {
    constexpr int QT = QPT * 16, DT = DPT * 16;
    float* qtile = sm;
    float* dtile = qtile + QT * 132;
    float* mdv = dtile + DT * 132;
    float* red = mdv + DT;
    float* outred = red + 4 * 16 * QPT * 11;
    const float MUc[11] = {1.0f, 0.9f, 0.7f, 0.5f, 0.3f, 0.1f, -0.1f, -0.3f, -0.5f, -0.7f, -0.9f};
    const float NC[11]  = {-500000.0f, -50.f, -50.f, -50.f, -50.f, -50.f, -50.f, -50.f, -50.f, -50.f, -50.f};
    int t = threadIdx.x;
    int tq = t & 15, td = t >> 4;
    if (t < 11) outred[t] = 0.f;
    for (int i = t; i < QT * 32; i += 256) {
        int r = i >> 5, c = i & 31;
        int qrow = q0 + r;
        float4 val = make_float4(0.f, 0.f, 0.f, 0.f);
        if (qrow < QL) {
            float s = invQ[qbase + qrow];
            float4 g = *(const float4*)(Q + (size_t)(qbase + qrow) * DD + 4 * c);
            val = make_float4(g.x * s, g.y * s, g.z * s, g.w * s);
        }
        *(float4*)&qtile[r * 132 + 4 * c] = val;
    }
    float ps[QPT][11];
#pragma unroll
    for (int i = 0; i < QPT; i++)
#pragma unroll
        for (int kk = 0; kk < 11; kk++) ps[i][kk] = 0.f;

    for (int d0 = 0; d0 < DL; d0 += DT) {
        for (int i = t; i < DT * 32; i += 256) {
            int r = i >> 5, c = i & 31;
            int drow = d0 + r;
            float4 val = make_float4(0.f, 0.f, 0.f, 0.f);
            if (drow < DL) {
                float s = invD[dbase + drow];
                float4 g = *(const float4*)(D + (size_t)(dbase + drow) * DD + 4 * c);
                val = make_float4(g.x * s, g.y * s, g.z * s, g.w * s);
            }
            *(float4*)&dtile[r * 132 + 4 * c] = val;
        }
        if (t < DT) mdv[t] = (d0 + t < DL) ? md[mdbase + d0 + t] : 0.f;
        __syncthreads();
        float dot[QPT][DPT];
#pragma unroll
        for (int i = 0; i < QPT; i++)
#pragma unroll
            for (int j = 0; j < DPT; j++) dot[i][j] = 0.f;
#pragma unroll 2
        for (int e4 = 0; e4 < 32; e4++) {
            float4 qv[QPT], dv[DPT];
#pragma unroll
            for (int i = 0; i < QPT; i++) qv[i] = *(const float4*)&qtile[(tq + 16 * i) * 132 + 4 * e4];
#pragma unroll
            for (int j = 0; j < DPT; j++) dv[j] = *(const float4*)&dtile[(td + 16 * j) * 132 + 4 * e4];
#pragma unroll
            for (int i = 0; i < QPT; i++)
#pragma unroll
                for (int j = 0; j < DPT; j++)
                    dot[i][j] += qv[i].x * dv[j].x + qv[i].y * dv[j].y + qv[i].z * dv[j].z + qv[i].w * dv[j].w;
        }
#pragma unroll
        for (int j = 0; j < DPT; j++) {
            float m = mdv[td + 16 * j];
#pragma unroll
            for (int i = 0; i < QPT; i++) {
                float sim = dot[i][j];
#pragma unroll
                for (int kk = 0; kk < 11; kk++) {
                    float df = sim - MUc[kk];
                    ps[i][kk] = fmaf(__expf(df * df * NC[kk]), m, ps[i][kk]);
                }
            }
        }
        __syncthreads();
    }
#pragma unroll
    for (int i = 0; i < QPT; i++)
#pragma unroll
        for (int kk = 0; kk < 11; kk++) {
            ps[i][kk] += __shfl_xor(ps[i][kk], 16, 64);
            ps[i][kk] += __shfl_xor(ps[i][kk], 32, 64);
        }
    int w = t >> 6;
    if ((t & 63) < 16) {
#pragma unroll
        for (int i = 0; i < QPT; i++)
#pragma unroll
            for (int kk = 0; kk < 11; kk++) red[(w * 16 + tq) * (QPT * 11) + i * 11 + kk] = ps[i][kk];
    }
    __syncthreads();
    for (int i = t; i < 16 * QPT * 11; i += 256) {
        int tq2 = i / (QPT * 11);
        int rem = i - tq2 * (QPT * 11);
        int qi = rem / 11, kk = rem - qi * 11;
        float s = red[(0 * 16 + tq2) * (QPT * 11) + qi * 11 + kk] + red[(1 * 16 + tq2) * (QPT * 11) + qi * 11 + kk]
                + red[(2 * 16 + tq2) * (QPT * 11) + qi * 11 + kk] + red[(3 * 16 + tq2) * (QPT * 11) + qi * 11 + kk];
        int qrow = q0 + tq2 + 16 * qi;
        if (qrow < QL) {
            float lps = logf(fmaxf(s, 1e-10f)) * mq[qbase + qrow] * 0.01f;
            atomicAdd(&outred[kk], lps);
        }
    }
    __syncthreads();
    if (t < 11) atomicAdd(&out[t], outred[t]);
}

__global__ __launch_bounds__(256) void knrm_all(
    const float* __restrict__ eq, const float* __restrict__ inv_eq, const float* __restrict__ mask_q,
    const float* __restrict__ ed, const float* __restrict__ inv_ed, const float* __restrict__ mask_d,
    const float* __restrict__ eb, const float* __restrict__ inv_eb, const float* __restrict__ mask_db,
    const float* __restrict__ enc_d, const float* __restrict__ inv_encd,
    const float* __restrict__ enc_b, const float* __restrict__ inv_encb,
    const float* __restrict__ enc_dcq, const float* __restrict__ inv_encdcq, const float* __restrict__ mask_dcq,
    float* __restrict__ qdk, float* __restrict__ qbk,
    float* __restrict__ kq, float* __restrict__ kd, float* __restrict__ kb) {
    __shared__ float sm[14155];
    int blk = blockIdx.x;
    if (blk < 32) {
        int b = blk;
        knrm_core<2, 4>(sm, eq, inv_eq, mask_q, QL_, 0, b * QL_, ed, inv_ed, mask_d, DL_, b * DL_, b * DL_, qdk + b * 11);
    } else if (blk < 64) {
        int b = blk - 32;
        knrm_core<2, 4>(sm, eq, inv_eq, mask_q, QL_, 0, b * QL_, eb, inv_eb, mask_db, BL_, b * BL_, b * BL_, qbk + b * 11);
    } else {
        int u = blk - 64;
        int sub = u % 10;
        int ib = u / 10;
        int b = ib & 31, inst = ib >> 5;
        int dbase = b * (MN_ * ML_) + inst * ML_;
        if (sub == 0)
            knrm_core<4, 1>(sm, eq, inv_eq, mask_q, QL_, 0, b * QL_, enc_dcq, inv_encdcq, mask_dcq, ML_, dbase, dbase,
                            kq + (size_t)(inst * BB + b) * 11);
        else if (sub == 1)
            knrm_core<4, 1>(sm, enc_d, inv_encd, mask_d, DL_, 0, b * DL_, enc_dcq, inv_encdcq, mask_dcq, ML_, dbase, dbase,
                            kd + (size_t)(inst * BB + b) * 11);
        else
            knrm_core<4, 1>(sm, enc_b, inv_encb, mask_db, BL_, (sub - 2) * 64, b * BL_, enc_dcq, inv_encdcq, mask_dcq, ML_,
                            dbase, dbase, kb + (size_t)(inst * BB + b) * 11);
    }
}

// ---------------- final combine ----------------
__device__ inline float dot11(const float* w, const float* x) {
    float s = 0.f;
#pragma unroll
    for (int k = 0; k < 11; k++) s += w[k] * x[k];
    return s;
}

__global__ void final_kernel(const float* __restrict__ qdk, const float* __restrict__ qbk,
                             const float* __restrict__ kq, const float* __restrict__ kd,
                             const float* __restrict__ kb,
                             const float* qdW, const float* qdb, const float* qbW, const float* qbb,
                             const float* qcqW, const float* qcqb, const float* dcqW, const float* dcqb,
                             const float* bcqW, const float* bcqb, const float* expW, const float* expb,
                             const float* combW, const float* combb, float* __restrict__ out) {
    int b = threadIdx.x;
    if (b >= BB) return;
    float qd = tanhf(dot11(qdW, qdk + b * 11) + qdb[0]);
    float qb = tanhf(dot11(qbW, qbk + b * 11) + qbb[0]);
    float qcqd = 0.f, qcqb2 = 0.f;
    for (int i = 0; i < MN_; i++) {
        int base = (i * BB + b) * 11;
        float r  = tanhf(dot11(qcqW, kq + base) + qcqb[0]);
        float da = tanhf(dot11(dcqW, kd + base) + dcqb[0]);
        float ba = tanhf(dot11(bcqW, kb + base) + bcqb[0]);
        qcqd += r * da;
        qcqb2 += r * ba;
    }
    float qcq = expW[0] * qcqd + expW[1] * qcqb2 + expb[0];
    out[b] = tanhf(combW[0] * qd + combW[1] * qb + combW[2] * qcq + combb[0]);
}

extern "C" void kernel_launch(void* const* d_in, const int* in_sizes, int n_in,
                              void* d_out, int out_size, void* d_ws, size_t ws_size,
                              hipStream_t stream) {
    const int*   in_q    = (const int*)d_in[0];
    const int*   in_d    = (const int*)d_in[1];
    const int*   in_dcq  = (const int*)d_in[2];
    const int*   in_db   = (const int*)d_in[3];
    const float* mask_q  = (const float*)d_in[4];
    const float* mask_d  = (const float*)d_in[5];
    const float* mask_dcq= (const float*)d_in[6];
    const float* mask_db = (const float*)d_in[7];
    const float* emb     = (const float*)d_in[8];
    const float* Wq = (const float*)d_in[9];   const float* bq = (const float*)d_in[10];
    const float* Wk = (const float*)d_in[11];  const float* bk = (const float*)d_in[12];
    const float* Wv = (const float*)d_in[13];  const float* bv = (const float*)d_in[14];
    const float* Wo = (const float*)d_in[15];  const float* bo = (const float*)d_in[16];
    const float* tW = (const float*)d_in[17];  const float* tb = (const float*)d_in[18];
    const float* qdW = (const float*)d_in[19]; const float* qdb = (const float*)d_in[20];
    const float* qbW = (const float*)d_in[21]; const float* qbb = (const float*)d_in[22];
    const float* qcqW = (const float*)d_in[23];const float* qcqb = (const float*)d_in[24];
    const float* dcqW = (const float*)d_in[25];const float* dcqb = (const float*)d_in[26];
    const float* bcqW = (const float*)d_in[27];const float* bcqb = (const float*)d_in[28];
    const float* expW = (const float*)d_in[29];const float* expb = (const float*)d_in[30];
    const float* combW = (const float*)d_in[31];const float* combb = (const float*)d_in[32];
    float* out = (float*)d_out;

    float* ws = (float*)d_ws;
    size_t off = 0;
    auto alloc = [&](size_t n) { float* p = ws + off; off += n; return p; };
    float* x_all = alloc((size_t)R_GATHER * DD);   // [dcq|d|b|eq] embeddings / projected dcq
    float* qbuf  = alloc((size_t)R_ALL * DD);      // q projections; reused as enc_all after attn
    float* kbuf  = alloc((size_t)R_ALL * DD);
    float* vbuf  = alloc((size_t)R_ALL * DD);
    float* ybuf  = alloc((size_t)R_ALL * DD);      // rows [0,4096): raw dcq emb before t-proj
    float* inv_eq  = alloc(ROWS_EQ);
    float* inv_ed  = alloc(ROWS_D);
    float* inv_eb  = alloc(ROWS_B);
    float* inv_enc = alloc(R_ALL);
    float* qdk = alloc(BB * 11);                   // knrm atomic outs (contiguous, zeroed in gather)
    float* qbk = alloc(BB * 11);
    float* kq  = alloc(MN_ * BB * 11);
    float* kd  = alloc(MN_ * BB * 11);
    float* kb  = alloc(MN_ * BB * 11);
    (void)ws_size; (void)in_sizes; (void)n_in; (void)out_size;

    const float* eq      = x_all + (size_t)R_ALL * DD;
    const float* ed      = x_all + (size_t)ROWS_DCQ * DD;
    const float* eb      = x_all + (size_t)(ROWS_DCQ + ROWS_D) * DD;
    float* enc_all = qbuf;
    const float* enc_dcq = enc_all;
    const float* enc_d   = enc_all + (size_t)ROWS_DCQ * DD;
    const float* enc_b   = enc_all + (size_t)(ROWS_DCQ + ROWS_D) * DD;
    const float* inv_encdcq = inv_enc;
    const float* inv_encd   = inv_enc + ROWS_DCQ;
    const float* inv_encb   = inv_enc + ROWS_DCQ + ROWS_D;

    // 1. gathers + emb norms + zero knrm accumulators         (grid 2896 + 36)
    gather_all<<<2932, 256, 0, stream>>>(in_q, in_d, in_dcq, in_db, emb,
                                         x_all, ybuf, inv_eq, inv_ed, inv_eb, qdk, 9152);
    // 2. t-projection: raw dcq emb (ybuf[0:4096]) -> x_all[0:4096]
    lin_kernel<<<ROWS_DCQ / 128, 256, 0, stream>>>(ybuf, tW, tb, x_all, nullptr);
    // 3. q/k/v projections over all 22528 rows in one launch
    qkv_all<<<3 * (R_ALL / 128), 256, 0, stream>>>(x_all, Wq, bq, Wk, bk, Wv, bv, qbuf, kbuf, vbuf);
    // 4. all three attentions in one launch
    attn_all<<<768, 1024, 0, stream>>>(qbuf, kbuf, vbuf, ybuf);
    // 5. out-projection over all rows + fused enc norms (qbuf becomes enc_all)
    lin_kernel<<<R_ALL / 128, 256, 0, stream>>>(ybuf, Wo, bo, enc_all, inv_enc);
    // 6. all 26 KNRM reductions
    knrm_all<<<2624, 256, 0, stream>>>(eq, inv_eq, mask_q, ed, inv_ed, mask_d, eb, inv_eb, mask_db,
                                       enc_d, inv_encd, enc_b, inv_encb, enc_dcq, inv_encdcq, mask_dcq,
                                       qdk, qbk, kq, kd, kb);
    // 7. final combine
    final_kernel<<<1, 64, 0, stream>>>(qdk, qbk, kq, kd, kb,
                                       qdW, qdb, qbW, qbb, qcqW, qcqb, dcqW, dcqb,
                                       bcqW, bcqb, expW, expb, combW, combb, out);
}

// Round 5
// 385.088 us; speedup vs baseline: 12.9872x; 1.0177x over previous
//
#include <hip/hip_runtime.h>
#include <hip/hip_bf16.h>

// Model dims
#define BB 32
#define QL_ 20
#define DL_ 64
#define BL_ 512
#define MN_ 8
#define ML_ 16
#define DD 128
#define HH 8

// concatenated row-space for MHA: [dcq | d | b]; eq appended for gather only
#define ROWS_DCQ 4096
#define ROWS_D   2048
#define ROWS_B   16384
#define R_ALL    22528
#define ROWS_EQ  640
#define R_GATHER 23168

typedef float f2 __attribute__((ext_vector_type(2)));

// ---------------- fused gather (+norms) + zero of knrm accumulators ----------------
__global__ __launch_bounds__(256) void gather_all(
    const int* __restrict__ in_q, const int* __restrict__ in_d,
    const int* __restrict__ in_dcq, const int* __restrict__ in_db,
    const float* __restrict__ emb, float* __restrict__ x_all, float* __restrict__ ytmp,
    float* __restrict__ inv_eq, float* __restrict__ inv_ed, float* __restrict__ inv_eb,
    float* __restrict__ zero_p, int nzero) {
    int blk = blockIdx.x;
    if (blk >= 2896) {                      // zero tail
        int i = (blk - 2896) * 256 + threadIdx.x;
        if (i < nzero) zero_p[i] = 0.f;
        return;
    }
    int t = blk * 256 + threadIdx.x;
    int r = t >> 5, c = t & 31;
    const int* idx; float* outp; float* invp; int lr;
    if (r < ROWS_DCQ)              { idx = in_dcq; outp = ytmp + (size_t)r * DD;  invp = nullptr; lr = r; }
    else if (r < ROWS_DCQ + ROWS_D){ idx = in_d;   outp = x_all + (size_t)r * DD; invp = inv_ed;  lr = r - ROWS_DCQ; }
    else if (r < R_ALL)            { idx = in_db;  outp = x_all + (size_t)r * DD; invp = inv_eb;  lr = r - (ROWS_DCQ + ROWS_D); }
    else                           { idx = in_q;   outp = x_all + (size_t)r * DD; invp = inv_eq;  lr = r - R_ALL; }
    float4 val = ((const float4*)(emb + (size_t)idx[lr] * DD))[c];
    ((float4*)outp)[c] = val;
    float ss = val.x * val.x + val.y * val.y + val.z * val.z + val.w * val.w;
    ss += __shfl_xor(ss, 1, 64);
    ss += __shfl_xor(ss, 2, 64);
    ss += __shfl_xor(ss, 4, 64);
    ss += __shfl_xor(ss, 8, 64);
    ss += __shfl_xor(ss, 16, 64);
    if (c == 0 && invp) invp[lr] = 1.0f / fmaxf(sqrtf(ss), 1e-12f);
}

// ---------------- linear 128->128 + relu, 8x8 register tile (x from global/L2) -------
__device__ __forceinline__ void linear_body(float* __restrict__ wT, float* __restrict__ bs,
                                            const float* __restrict__ in, const float* __restrict__ W,
                                            const float* __restrict__ bias, float* __restrict__ out,
                                            float* __restrict__ inv_out, int block) {
    int t = threadIdx.x;
    for (int i = t; i < DD * DD; i += 256) {
        int o = i >> 7, e = i & 127;
        wT[e * 132 + o] = W[i];
    }
    if (t < 128) bs[t] = bias[t];
    __syncthreads();
    int og = t & 15, rg = t >> 4;
    int rowbase = block * 128 + rg * 8;
    f2 acc[8][4];
#pragma unroll
    for (int r = 0; r < 8; r++)
#pragma unroll
        for (int p = 0; p < 4; p++) acc[r][p] = f2{0.f, 0.f};
    for (int e4 = 0; e4 < 32; e4++) {
        float4 xv[8];
#pragma unroll
        for (int r = 0; r < 8; r++)
            xv[r] = *(const float4*)&in[(size_t)(rowbase + r) * DD + 4 * e4];
#pragma unroll
        for (int ee = 0; ee < 4; ee++) {
            int e = 4 * e4 + ee;
            float4 wa = *(const float4*)&wT[e * 132 + 8 * og];
            float4 wb = *(const float4*)&wT[e * 132 + 8 * og + 4];
            f2 w0 = {wa.x, wa.y}, w1 = {wa.z, wa.w}, w2 = {wb.x, wb.y}, w3 = {wb.z, wb.w};
#pragma unroll
            for (int r = 0; r < 8; r++) {
                float x = ((const float*)&xv[r])[ee];
                f2 x2 = {x, x};
                acc[r][0] = __builtin_elementwise_fma(x2, w0, acc[r][0]);
                acc[r][1] = __builtin_elementwise_fma(x2, w1, acc[r][1]);
                acc[r][2] = __builtin_elementwise_fma(x2, w2, acc[r][2]);
                acc[r][3] = __builtin_elementwise_fma(x2, w3, acc[r][3]);
            }
        }
    }
    float4 ba = *(const float4*)&bs[8 * og];
    float4 bbv = *(const float4*)&bs[8 * og + 4];
    float ss[8];
#pragma unroll
    for (int r = 0; r < 8; r++) {
        float o0 = fmaxf(acc[r][0].x + ba.x, 0.f);
        float o1 = fmaxf(acc[r][0].y + ba.y, 0.f);
        float o2 = fmaxf(acc[r][1].x + ba.z, 0.f);
        float o3 = fmaxf(acc[r][1].y + ba.w, 0.f);
        float o4 = fmaxf(acc[r][2].x + bbv.x, 0.f);
        float o5 = fmaxf(acc[r][2].y + bbv.y, 0.f);
        float o6 = fmaxf(acc[r][3].x + bbv.z, 0.f);
        float o7 = fmaxf(acc[r][3].y + bbv.w, 0.f);
        float4 s1 = {o0, o1, o2, o3}, s2 = {o4, o5, o6, o7};
        float* op = out + (size_t)(rowbase + r) * DD + 8 * og;
        *(float4*)op = s1;
        *(float4*)(op + 4) = s2;
        ss[r] = o0 * o0 + o1 * o1 + o2 * o2 + o3 * o3 + o4 * o4 + o5 * o5 + o6 * o6 + o7 * o7;
    }
    if (inv_out) {
#pragma unroll
        for (int r = 0; r < 8; r++) {
            ss[r] += __shfl_xor(ss[r], 1, 64);
            ss[r] += __shfl_xor(ss[r], 2, 64);
            ss[r] += __shfl_xor(ss[r], 4, 64);
            ss[r] += __shfl_xor(ss[r], 8, 64);
        }
#pragma unroll
        for (int r = 0; r < 8; r++)
            if (og == r) inv_out[rowbase + r] = 1.0f / fmaxf(sqrtf(ss[r]), 1e-12f);
    }
}

__global__ __launch_bounds__(256) void lin_kernel(const float* __restrict__ in, const float* __restrict__ W,
                                                  const float* __restrict__ bias, float* __restrict__ out,
                                                  float* __restrict__ inv_out) {
    __shared__ float wT[DD * 132];
    __shared__ float bs[DD];
    linear_body(wT, bs, in, W, bias, out, inv_out, blockIdx.x);
}

__global__ __launch_bounds__(256) void qkv_all(const float* __restrict__ x,
                                               const float* __restrict__ Wq, const float* __restrict__ bq,
                                               const float* __restrict__ Wk, const float* __restrict__ bk,
                                               const float* __restrict__ Wv, const float* __restrict__ bv,
                                               float* __restrict__ q, float* __restrict__ k, float* __restrict__ v) {
    __shared__ float wT[DD * 132];
    __shared__ float bs[DD];
    int sel = blockIdx.x / 176, blk = blockIdx.x % 176;
    const float* W = (sel == 0) ? Wq : (sel == 1) ? Wk : Wv;
    const float* B = (sel == 0) ? bq : (sel == 1) ? bk : bv;
    float* O = (sel == 0) ? q : (sel == 1) ? k : v;
    linear_body(wT, bs, x, W, B, O, nullptr, blk);
}

// ---------------- L=512 attention: shuffle-free row-pair scheme ----------------
// 16 waves = 4 q-slabs (qw) x 4 key-groups (kg). Lane owns rows r0=qw*128+lane and r0+64,
// packed as f2 {row0, row1}. K/V rows broadcast from LDS, splat into both halves -> no
// cross-lane ops at all. Partials merged through LDS in 3 rounds (kg=1..3 -> kg=0).
// Softmax without max-shift: algebraically identical (shift-invariance); scores are tiny.
__device__ __forceinline__ void attn512_v5(float* __restrict__ sm,
                                           const float* __restrict__ q, const float* __restrict__ k,
                                           const float* __restrict__ v, float* __restrict__ y, int bh) {
    float* ks = sm;
    float* vs = sm + 512 * 16;
    int h = bh & 7, b = bh >> 3;
    int t = threadIdx.x;
    const size_t base = (size_t)b * 512 * DD + h * 16;
    for (int i = t; i < 512 * 4; i += 1024) {
        int j = i >> 2, c = i & 3;
        *(float4*)&ks[j * 16 + 4 * c] = *(const float4*)&k[base + (size_t)j * DD + 4 * c];
        *(float4*)&vs[j * 16 + 4 * c] = *(const float4*)&v[base + (size_t)j * DD + 4 * c];
    }
    int w = t >> 6, lane = t & 63;
    int kg = w & 3, qw = w >> 2;
    int r0 = qw * 128 + lane;
    const float* qp0 = q + base + (size_t)r0 * DD;
    const float* qp1 = qp0 + 64 * DD;
    float qA[16], qB[16];
#pragma unroll
    for (int c = 0; c < 4; c++) {
        *(float4*)&qA[4 * c] = *(const float4*)(qp0 + 4 * c);
        *(float4*)&qB[4 * c] = *(const float4*)(qp1 + 4 * c);
    }
    f2 qv[16];
#pragma unroll
    for (int e = 0; e < 16; e++) qv[e] = f2{qA[e] * 0.25f, qB[e] * 0.25f};
    f2 acc[16];
    f2 l2 = {0.f, 0.f};
#pragma unroll
    for (int e = 0; e < 16; e++) acc[e] = f2{0.f, 0.f};
    __syncthreads();
    int j0 = kg * 128;
    for (int j = j0; j < j0 + 128; j++) {
        float kk[16], vv[16];
#pragma unroll
        for (int c = 0; c < 4; c++) {
            *(float4*)&kk[4 * c] = *(const float4*)&ks[j * 16 + 4 * c];
            *(float4*)&vv[4 * c] = *(const float4*)&vs[j * 16 + 4 * c];
        }
        f2 s0 = qv[0] * f2{kk[0], kk[0]};
        f2 s1 = qv[1] * f2{kk[1], kk[1]};
        f2 s2 = qv[2] * f2{kk[2], kk[2]};
        f2 s3 = qv[3] * f2{kk[3], kk[3]};
#pragma unroll
        for (int e = 4; e < 16; e += 4) {
            s0 = __builtin_elementwise_fma(qv[e + 0], f2{kk[e + 0], kk[e + 0]}, s0);
            s1 = __builtin_elementwise_fma(qv[e + 1], f2{kk[e + 1], kk[e + 1]}, s1);
            s2 = __builtin_elementwise_fma(qv[e + 2], f2{kk[e + 2], kk[e + 2]}, s2);
            s3 = __builtin_elementwise_fma(qv[e + 3], f2{kk[e + 3], kk[e + 3]}, s3);
        }
        f2 d = (s0 + s1) + (s2 + s3);
        f2 p = {__expf(d.x), __expf(d.y)};
        l2 += p;
#pragma unroll
        for (int e = 0; e < 16; e++)
            acc[e] = __builtin_elementwise_fma(p, f2{vv[e], vv[e]}, acc[e]);
    }
    __syncthreads();   // staging dead; reuse sm for partials (512 rows x 17 floats = 34.8 KB)
#pragma unroll
    for (int g = 1; g < 4; g++) {
        if (kg == g) {
            float* p0 = &sm[r0 * 17];
            float* p1 = &sm[(r0 + 64) * 17];
#pragma unroll
            for (int e = 0; e < 16; e++) { p0[e] = acc[e].x; p1[e] = acc[e].y; }
            p0[16] = l2.x;
            p1[16] = l2.y;
        }
        __syncthreads();
        if (kg == 0) {
            const float* p0 = &sm[r0 * 17];
            const float* p1 = &sm[(r0 + 64) * 17];
#pragma unroll
            for (int e = 0; e < 16; e++) { acc[e].x += p0[e]; acc[e].y += p1[e]; }
            l2.x += p0[16];
            l2.y += p1[16];
        }
        __syncthreads();
    }
    if (kg == 0) {
        float ix = 1.0f / l2.x, iy = 1.0f / l2.y;
        float o0[16], o1[16];
#pragma unroll
        for (int e = 0; e < 16; e++) { o0[e] = acc[e].x * ix; o1[e] = acc[e].y * iy; }
        float* yp0 = y + base + (size_t)r0 * DD;
        float* yp1 = yp0 + 64 * DD;
#pragma unroll
        for (int c = 0; c < 4; c++) {
            *(float4*)(yp0 + 4 * c) = *(const float4*)&o0[4 * c];
            *(float4*)(yp1 + 4 * c) = *(const float4*)&o1[4 * c];
        }
    }
}

// ---------------- small-L attention (e-split; key loops are short, shfl cost negligible) --
template <int L, int NQ>
__device__ __forceinline__ void attn_body(float* __restrict__ sm, const float* __restrict__ q,
                                          const float* __restrict__ k, const float* __restrict__ v,
                                          float* __restrict__ y, int bh) {
    constexpr int WAVES = 16;
    constexpr int WQ = L / (32 * NQ);
    constexpr int KG = WAVES / WQ;
    constexpr int KPG = L / KG;
    float* ks = sm;
    float* vs = sm + L * 16;
    int h = bh & 7, b = bh >> 3;
    int t = threadIdx.x;
    const size_t base = (size_t)b * L * DD + h * 16;
    for (int i = t; i < L * 4; i += 1024) {
        int j = i >> 2, c = i & 3;
        *(float4*)&ks[j * 16 + 4 * c] = *(const float4*)&k[base + (size_t)j * DD + 4 * c];
        *(float4*)&vs[j * 16 + 4 * c] = *(const float4*)&v[base + (size_t)j * DD + 4 * c];
    }
    int w = t >> 6, lane = t & 63;
    int ls = lane & 31, eh = lane >> 5;
    int kg = w % KG, qw = w / KG;
    int qb2 = qw * 32 * NQ;
    f2 qv[NQ][4];
#pragma unroll
    for (int n = 0; n < NQ; n++) {
        int qr = qb2 + ls + 32 * n;
        const float* qp = q + base + (size_t)qr * DD + eh * 8;
        float4 a = *(const float4*)qp;
        float4 b4 = *(const float4*)(qp + 4);
        qv[n][0] = f2{a.x, a.y};   qv[n][1] = f2{a.z, a.w};
        qv[n][2] = f2{b4.x, b4.y}; qv[n][3] = f2{b4.z, b4.w};
    }
    f2 acc[NQ][4];
    float l[NQ];
#pragma unroll
    for (int n = 0; n < NQ; n++) {
#pragma unroll
        for (int m = 0; m < 4; m++) acc[n][m] = f2{0.f, 0.f};
        l[n] = 0.f;
    }
    __syncthreads();
    for (int j = kg * KPG; j < (kg + 1) * KPG; j++) {
        float4 ka = *(const float4*)&ks[j * 16 + eh * 8];
        float4 kb2 = *(const float4*)&ks[j * 16 + eh * 8 + 4];
        float4 va = *(const float4*)&vs[j * 16 + eh * 8];
        float4 vb2 = *(const float4*)&vs[j * 16 + eh * 8 + 4];
        f2 kk0 = {ka.x, ka.y}, kk1 = {ka.z, ka.w}, kk2 = {kb2.x, kb2.y}, kk3 = {kb2.z, kb2.w};
        f2 vv0 = {va.x, va.y}, vv1 = {va.z, va.w}, vv2 = {vb2.x, vb2.y}, vv3 = {vb2.z, vb2.w};
#pragma unroll
        for (int n = 0; n < NQ; n++) {
            f2 d2 = qv[n][0] * kk0;
            d2 = __builtin_elementwise_fma(qv[n][1], kk1, d2);
            d2 = __builtin_elementwise_fma(qv[n][2], kk2, d2);
            d2 = __builtin_elementwise_fma(qv[n][3], kk3, d2);
            float sh = d2.x + d2.y;
            float s = sh + __shfl_xor(sh, 32, 64);
            float p = __expf(s * 0.25f);
            l[n] += p;
            f2 p2 = {p, p};
            acc[n][0] = __builtin_elementwise_fma(p2, vv0, acc[n][0]);
            acc[n][1] = __builtin_elementwise_fma(p2, vv1, acc[n][1]);
            acc[n][2] = __builtin_elementwise_fma(p2, vv2, acc[n][2]);
            acc[n][3] = __builtin_elementwise_fma(p2, vv3, acc[n][3]);
        }
    }
    __syncthreads();   // done with ks/vs; reuse sm for partials
    if (kg > 0) {
#pragma unroll
        for (int n = 0; n < NQ; n++) {
            int qr = qb2 + ls + 32 * n;
            float* pp = &sm[((kg - 1) * L + qr) * 20 + eh * 10];
            *(f2*)&pp[0] = acc[n][0];
            *(f2*)&pp[2] = acc[n][1];
            *(f2*)&pp[4] = acc[n][2];
            *(f2*)&pp[6] = acc[n][3];
            pp[8] = l[n];
        }
    }
    __syncthreads();
    if (kg == 0) {
#pragma unroll
        for (int n = 0; n < NQ; n++) {
            int qr = qb2 + ls + 32 * n;
            f2 a0 = acc[n][0], a1 = acc[n][1], a2 = acc[n][2], a3 = acc[n][3];
            float lt = l[n];
#pragma unroll
            for (int g = 1; g < KG; g++) {
                const float* pp = &sm[((g - 1) * L + qr) * 20 + eh * 10];
                a0 += *(const f2*)&pp[0];
                a1 += *(const f2*)&pp[2];
                a2 += *(const f2*)&pp[4];
                a3 += *(const f2*)&pp[6];
                lt += pp[8];
            }
            float inv = 1.0f / lt;
            float4 o1 = {a0.x * inv, a0.y * inv, a1.x * inv, a1.y * inv};
            float4 o2 = {a2.x * inv, a2.y * inv, a3.x * inv, a3.y * inv};
            float* yp = y + base + (size_t)qr * DD + eh * 8;
            *(float4*)yp = o1;
            *(float4*)(yp + 4) = o2;
        }
    }
}

__global__ __launch_bounds__(1024) void attn_all(const float* __restrict__ qb_, const float* __restrict__ kb_,
                                                 const float* __restrict__ vb_, float* __restrict__ yb_) {
    __shared__ float sm[16384];            // 64 KB
    int blk = blockIdx.x;
    if (blk < 256) {
        const size_t off = (size_t)(ROWS_DCQ + ROWS_D) * DD;
        attn512_v5(sm, qb_ + off, kb_ + off, vb_ + off, yb_ + off, blk);
    } else if (blk < 512) {
        attn_body<128, 1>(sm, qb_, kb_, vb_, yb_, blk - 256);
    } else {
        const size_t off = (size_t)ROWS_DCQ * DD;
        attn_body<64, 1>(sm, qb_ + off, kb_ + off, vb_ + off, yb_ + off, blk - 512);
    }
}

// ---------------- KNRM core: register-tiled sims + gaussian kernels ----------------
template <int QPT, int DPT>
__device__ void knrm_core(float* __restrict__ sm,
                          const float* __restrict__ Q, const float* __restrict__ invQ,
                          const float* __restrict__ mq, int QL, int q0, int qbase,
                          const float* __restrict__ D, const float* __restrict__ invD,
                          const float* __restrict__ md, int DL, int dbase, int mdbase,
                          float* __restrict__ out) {
    constexpr int QT = QPT * 16, DT = DPT * 16;
    float* qtile = sm;
    float* dtile = qtile + QT * 132;
    float* mdv = dtile + DT * 132;
    float* red = mdv + DT;
    float* outred = red + 4 * 16 * QPT * 11;
    const float MUc[11] = {1.0f, 0.9f, 0.7f, 0.5f, 0.3f, 0.1f, -0.1f, -0.3f, -0.5f, -0.7f, -0.9f};
    const float NC[11]  = {-500000.0f, -50.f, -50.f, -50.f, -50.f, -50.f, -50.f, -50.f, -50.f, -50.f, -50.f};
    int t = threadIdx.x;
    int tq = t & 15, td = t >> 4;
    if (t < 11) outred[t] = 0.f;
    for (int i = t; i < QT * 32; i += 256) {
        int r = i >> 5, c = i & 31;
        int qrow = q0 + r;
        float4 val = make_float4(0.f, 0.f, 0.f, 0.f);
        if (qrow < QL) {
            float s = invQ[qbase + qrow];
            float4 g = *(const float4*)(Q + (size_t)(qbase + qrow) * DD + 4 * c);
            val = make_float4(g.x * s, g.y * s, g.z * s, g.w * s);
        }
        *(float4*)&qtile[r * 132 + 4 * c] = val;
    }
    float ps[QPT][11];
#pragma unroll
    for (int i = 0; i < QPT; i++)
#pragma unroll
        for (int kk = 0; kk < 11; kk++) ps[i][kk] = 0.f;

    for (int d0 = 0; d0 < DL; d0 += DT) {
        for (int i = t; i < DT * 32; i += 256) {
            int r = i >> 5, c = i & 31;
            int drow = d0 + r;
            float4 val = make_float4(0.f, 0.f, 0.f, 0.f);
            if (drow < DL) {
                float s = invD[dbase + drow];
                float4 g = *(const float4*)(D + (size_t)(dbase + drow) * DD + 4 * c);
                val = make_float4(g.x * s, g.y * s, g.z * s, g.w * s);
            }
            *(float4*)&dtile[r * 132 + 4 * c] = val;
        }
        if (t < DT) mdv[t] = (d0 + t < DL) ? md[mdbase + d0 + t] : 0.f;
        __syncthreads();
        float dot[QPT][DPT];
#pragma unroll
        for (int i = 0; i < QPT; i++)
#pragma unroll
            for (int j = 0; j < DPT; j++) dot[i][j] = 0.f;
#pragma unroll 2
        for (int e4 = 0; e4 < 32; e4++) {
            float4 qv[QPT], dv[DPT];
#pragma unroll
            for (int i = 0; i < QPT; i++) qv[i] = *(const float4*)&qtile[(tq + 16 * i) * 132 + 4 * e4];
#pragma unroll
            for (int j = 0; j < DPT; j++) dv[j] = *(const float4*)&dtile[(td + 16 * j) * 132 + 4 * e4];
#pragma unroll
            for (int i = 0; i < QPT; i++)
#pragma unroll
                for (int j = 0; j < DPT; j++)
                    dot[i][j] += qv[i].x * dv[j].x + qv[i].y * dv[j].y + qv[i].z * dv[j].z + qv[i].w * dv[j].w;
        }
#pragma unroll
        for (int j = 0; j < DPT; j++) {
            float m = mdv[td + 16 * j];
#pragma unroll
            for (int i = 0; i < QPT; i++) {
                float sim = dot[i][j];
#pragma unroll
                for (int kk = 0; kk < 11; kk++) {
                    float df = sim - MUc[kk];
                    ps[i][kk] = fmaf(__expf(df * df * NC[kk]), m, ps[i][kk]);
                }
            }
        }
        __syncthreads();
    }
#pragma unroll
    for (int i = 0; i < QPT; i++)
#pragma unroll
        for (int kk = 0; kk < 11; kk++) {
            ps[i][kk] += __shfl_xor(ps[i][kk], 16, 64);
            ps[i][kk] += __shfl_xor(ps[i][kk], 32, 64);
        }
    int w = t >> 6;
    if ((t & 63) < 16) {
#pragma unroll
        for (int i = 0; i < QPT; i++)
#pragma unroll
            for (int kk = 0; kk < 11; kk++) red[(w * 16 + tq) * (QPT * 11) + i * 11 + kk] = ps[i][kk];
    }
    __syncthreads();
    for (int i = t; i < 16 * QPT * 11; i += 256) {
        int tq2 = i / (QPT * 11);
        int rem = i - tq2 * (QPT * 11);
        int qi = rem / 11, kk = rem - qi * 11;
        float s = red[(0 * 16 + tq2) * (QPT * 11) + qi * 11 + kk] + red[(1 * 16 + tq2) * (QPT * 11) + qi * 11 + kk]
                + red[(2 * 16 + tq2) * (QPT * 11) + qi * 11 + kk] + red[(3 * 16 + tq2) * (QPT * 11) + qi * 11 + kk];
        int qrow = q0 + tq2 + 16 * qi;
        if (qrow < QL) {
            float lps = logf(fmaxf(s, 1e-10f)) * mq[qbase + qrow] * 0.01f;
            atomicAdd(&outred[kk], lps);
        }
    }
    __syncthreads();
    if (t < 11) atomicAdd(&out[t], outred[t]);
}

__global__ __launch_bounds__(256) void knrm_all(
    const float* __restrict__ eq, const float* __restrict__ inv_eq, const float* __restrict__ mask_q,
    const float* __restrict__ ed, const float* __restrict__ inv_ed, const float* __restrict__ mask_d,
    const float* __restrict__ eb, const float* __restrict__ inv_eb, const float* __restrict__ mask_db,
    const float* __restrict__ enc_d, const float* __restrict__ inv_encd,
    const float* __restrict__ enc_b, const float* __restrict__ inv_encb,
    const float* __restrict__ enc_dcq, const float* __restrict__ inv_encdcq, const float* __restrict__ mask_dcq,
    float* __restrict__ qdk, float* __restrict__ qbk,
    float* __restrict__ kq, float* __restrict__ kd, float* __restrict__ kb) {
    __shared__ float sm[14155];
    int blk = blockIdx.x;
    if (blk < 32) {
        int b = blk;
        knrm_core<2, 4>(sm, eq, inv_eq, mask_q, QL_, 0, b * QL_, ed, inv_ed, mask_d, DL_, b * DL_, b * DL_, qdk + b * 11);
    } else if (blk < 64) {
        int b = blk - 32;
        knrm_core<2, 4>(sm, eq, inv_eq, mask_q, QL_, 0, b * QL_, eb, inv_eb, mask_db, BL_, b * BL_, b * BL_, qbk + b * 11);
    } else {
        int u = blk - 64;
        int sub = u % 10;
        int ib = u / 10;
        int b = ib & 31, inst = ib >> 5;
        int dbase = b * (MN_ * ML_) + inst * ML_;
        if (sub == 0)
            knrm_core<4, 1>(sm, eq, inv_eq, mask_q, QL_, 0, b * QL_, enc_dcq, inv_encdcq, mask_dcq, ML_, dbase, dbase,
                            kq + (size_t)(inst * BB + b) * 11);
        else if (sub == 1)
            knrm_core<4, 1>(sm, enc_d, inv_encd, mask_d, DL_, 0, b * DL_, enc_dcq, inv_encdcq, mask_dcq, ML_, dbase, dbase,
                            kd + (size_t)(inst * BB + b) * 11);
        else
            knrm_core<4, 1>(sm, enc_b, inv_encb, mask_db, BL_, (sub - 2) * 64, b * BL_, enc_dcq, inv_encdcq, mask_dcq, ML_,
                            dbase, dbase, kb + (size_t)(inst * BB + b) * 11);
    }
}

// ---------------- final combine ----------------
__device__ inline float dot11(const float* w, const float* x) {
    float s = 0.f;
#pragma unroll
    for (int k = 0; k < 11; k++) s += w[k] * x[k];
    return s;
}

__global__ void final_kernel(const float* __restrict__ qdk, const float* __restrict__ qbk,
                             const float* __restrict__ kq, const float* __restrict__ kd,
                             const float* __restrict__ kb,
                             const float* qdW, const float* qdb, const float* qbW, const float* qbb,
                             const float* qcqW, const float* qcqb, const float* dcqW, const float* dcqb,
                             const float* bcqW, const float* bcqb, const float* expW, const float* expb,
                             const float* combW, const float* combb, float* __restrict__ out) {
    int b = threadIdx.x;
    if (b >= BB) return;
    float qd = tanhf(dot11(qdW, qdk + b * 11) + qdb[0]);
    float qb = tanhf(dot11(qbW, qbk + b * 11) + qbb[0]);
    float qcqd = 0.f, qcqb2 = 0.f;
    for (int i = 0; i < MN_; i++) {
        int base = (i * BB + b) * 11;
        float r  = tanhf(dot11(qcqW, kq + base) + qcqb[0]);
        float da = tanhf(dot11(dcqW, kd + base) + dcqb[0]);
        float ba = tanhf(dot11(bcqW, kb + base) + bcqb[0]);
        qcqd += r * da;
        qcqb2 += r * ba;
    }
    float qcq = expW[0] * qcqd + expW[1] * qcqb2 + expb[0];
    out[b] = tanhf(combW[0] * qd + combW[1] * qb + combW[2] * qcq + combb[0]);
}

extern "C" void kernel_launch(void* const* d_in, const int* in_sizes, int n_in,
                              void* d_out, int out_size, void* d_ws, size_t ws_size,
                              hipStream_t stream) {
    const int*   in_q    = (const int*)d_in[0];
    const int*   in_d    = (const int*)d_in[1];
    const int*   in_dcq  = (const int*)d_in[2];
    const int*   in_db   = (const int*)d_in[3];
    const float* mask_q  = (const float*)d_in[4];
    const float* mask_d  = (const float*)d_in[5];
    const float* mask_dcq= (const float*)d_in[6];
    const float* mask_db = (const float*)d_in[7];
    const float* emb     = (const float*)d_in[8];
    const float* Wq = (const float*)d_in[9];   const float* bq = (const float*)d_in[10];
    const float* Wk = (const float*)d_in[11];  const float* bk = (const float*)d_in[12];
    const float* Wv = (const float*)d_in[13];  const float* bv = (const float*)d_in[14];
    const float* Wo = (const float*)d_in[15];  const float* bo = (const float*)d_in[16];
    const float* tW = (const float*)d_in[17];  const float* tb = (const float*)d_in[18];
    const float* qdW = (const float*)d_in[19]; const float* qdb = (const float*)d_in[20];
    const float* qbW = (const float*)d_in[21]; const float* qbb = (const float*)d_in[22];
    const float* qcqW = (const float*)d_in[23];const float* qcqb = (const float*)d_in[24];
    const float* dcqW = (const float*)d_in[25];const float* dcqb = (const float*)d_in[26];
    const float* bcqW = (const float*)d_in[27];const float* bcqb = (const float*)d_in[28];
    const float* expW = (const float*)d_in[29];const float* expb = (const float*)d_in[30];
    const float* combW = (const float*)d_in[31];const float* combb = (const float*)d_in[32];
    float* out = (float*)d_out;

    float* ws = (float*)d_ws;
    size_t off = 0;
    auto alloc = [&](size_t n) { float* p = ws + off; off += n; return p; };
    float* x_all = alloc((size_t)R_GATHER * DD);   // [dcq|d|b|eq] embeddings / projected dcq
    float* qbuf  = alloc((size_t)R_ALL * DD);      // q projections; reused as enc_all after attn
    float* kbuf  = alloc((size_t)R_ALL * DD);
    float* vbuf  = alloc((size_t)R_ALL * DD);
    float* ybuf  = alloc((size_t)R_ALL * DD);      // rows [0,4096): raw dcq emb before t-proj
    float* inv_eq  = alloc(ROWS_EQ);
    float* inv_ed  = alloc(ROWS_D);
    float* inv_eb  = alloc(ROWS_B);
    float* inv_enc = alloc(R_ALL);
    float* qdk = alloc(BB * 11);                   // knrm atomic outs (contiguous, zeroed in gather)
    float* qbk = alloc(BB * 11);
    float* kq  = alloc(MN_ * BB * 11);
    float* kd  = alloc(MN_ * BB * 11);
    float* kb  = alloc(MN_ * BB * 11);
    (void)ws_size; (void)in_sizes; (void)n_in; (void)out_size;

    const float* eq      = x_all + (size_t)R_ALL * DD;
    const float* ed      = x_all + (size_t)ROWS_DCQ * DD;
    const float* eb      = x_all + (size_t)(ROWS_DCQ + ROWS_D) * DD;
    float* enc_all = qbuf;
    const float* enc_dcq = enc_all;
    const float* enc_d   = enc_all + (size_t)ROWS_DCQ * DD;
    const float* enc_b   = enc_all + (size_t)(ROWS_DCQ + ROWS_D) * DD;
    const float* inv_encdcq = inv_enc;
    const float* inv_encd   = inv_enc + ROWS_DCQ;
    const float* inv_encb   = inv_enc + ROWS_DCQ + ROWS_D;

    // 1. gathers + emb norms + zero knrm accumulators         (grid 2896 + 36)
    gather_all<<<2932, 256, 0, stream>>>(in_q, in_d, in_dcq, in_db, emb,
                                         x_all, ybuf, inv_eq, inv_ed, inv_eb, qdk, 9152);
    // 2. t-projection: raw dcq emb (ybuf[0:4096]) -> x_all[0:4096]
    lin_kernel<<<ROWS_DCQ / 128, 256, 0, stream>>>(ybuf, tW, tb, x_all, nullptr);
    // 3. q/k/v projections over all 22528 rows in one launch
    qkv_all<<<3 * (R_ALL / 128), 256, 0, stream>>>(x_all, Wq, bq, Wk, bk, Wv, bv, qbuf, kbuf, vbuf);
    // 4. all three attentions in one launch
    attn_all<<<768, 1024, 0, stream>>>(qbuf, kbuf, vbuf, ybuf);
    // 5. out-projection over all rows + fused enc norms (qbuf becomes enc_all)
    lin_kernel<<<R_ALL / 128, 256, 0, stream>>>(ybuf, Wo, bo, enc_all, inv_enc);
    // 6. all 26 KNRM reductions
    knrm_all<<<2624, 256, 0, stream>>>(eq, inv_eq, mask_q, ed, inv_ed, mask_d, eb, inv_eb, mask_db,
                                       enc_d, inv_encd, enc_b, inv_encb, enc_dcq, inv_encdcq, mask_dcq,
                                       qdk, qbk, kq, kd, kb);
    // 7. final combine
    final_kernel<<<1, 64, 0, stream>>>(qdk, qbk, kq, kd, kb,
                                       qdW, qdb, qbW, qbb, qcqW, qcqb, dcqW, dcqb,
                                       bcqW, bcqb, expW, expb, combW, combb, out);
}

// Round 6
// 375.765 us; speedup vs baseline: 13.3094x; 1.0248x over previous
//
#include <hip/hip_runtime.h>
#include <hip/hip_bf16.h>

// Model dims
#define BB 32
#define QL_ 20
#define DL_ 64
#define BL_ 512
#define MN_ 8
#define ML_ 16
#define DD 128
#define HH 8

// concatenated row-space for MHA: [dcq | d | b]; eq appended for gather only
#define ROWS_DCQ 4096
#define ROWS_D   2048
#define ROWS_B   16384
#define R_ALL    22528
#define ROWS_EQ  640
#define R_GATHER 23168

typedef float f2 __attribute__((ext_vector_type(2)));

// ---------------- fused gather (+norms) + zero of knrm accumulators ----------------
__global__ __launch_bounds__(256) void gather_all(
    const int* __restrict__ in_q, const int* __restrict__ in_d,
    const int* __restrict__ in_dcq, const int* __restrict__ in_db,
    const float* __restrict__ emb, float* __restrict__ x_all, float* __restrict__ ytmp,
    float* __restrict__ inv_eq, float* __restrict__ inv_ed, float* __restrict__ inv_eb,
    float* __restrict__ zero_p, int nzero) {
    int blk = blockIdx.x;
    if (blk >= 2896) {                      // zero tail
        int i = (blk - 2896) * 256 + threadIdx.x;
        if (i < nzero) zero_p[i] = 0.f;
        return;
    }
    int t = blk * 256 + threadIdx.x;
    int r = t >> 5, c = t & 31;
    const int* idx; float* outp; float* invp; int lr;
    if (r < ROWS_DCQ)              { idx = in_dcq; outp = ytmp + (size_t)r * DD;  invp = nullptr; lr = r; }
    else if (r < ROWS_DCQ + ROWS_D){ idx = in_d;   outp = x_all + (size_t)r * DD; invp = inv_ed;  lr = r - ROWS_DCQ; }
    else if (r < R_ALL)            { idx = in_db;  outp = x_all + (size_t)r * DD; invp = inv_eb;  lr = r - (ROWS_DCQ + ROWS_D); }
    else                           { idx = in_q;   outp = x_all + (size_t)r * DD; invp = inv_eq;  lr = r - R_ALL; }
    float4 val = ((const float4*)(emb + (size_t)idx[lr] * DD))[c];
    ((float4*)outp)[c] = val;
    float ss = val.x * val.x + val.y * val.y + val.z * val.z + val.w * val.w;
    ss += __shfl_xor(ss, 1, 64);
    ss += __shfl_xor(ss, 2, 64);
    ss += __shfl_xor(ss, 4, 64);
    ss += __shfl_xor(ss, 8, 64);
    ss += __shfl_xor(ss, 16, 64);
    if (c == 0 && invp) invp[lr] = 1.0f / fmaxf(sqrtf(ss), 1e-12f);
}

// ---------------- linear 128->128 + relu, 8x8 register tile ----------------
__device__ __forceinline__ void linear_body(float* __restrict__ wT, float* __restrict__ bs,
                                            const float* __restrict__ in, const float* __restrict__ W,
                                            const float* __restrict__ bias, float* __restrict__ out,
                                            float* __restrict__ inv_out, int block) {
    int t = threadIdx.x;
    for (int i = t; i < DD * DD; i += 256) {
        int o = i >> 7, e = i & 127;
        wT[e * 132 + o] = W[i];
    }
    if (t < 128) bs[t] = bias[t];
    __syncthreads();
    int og = t & 15, rg = t >> 4;
    int rowbase = block * 128 + rg * 8;
    f2 acc[8][4];
#pragma unroll
    for (int r = 0; r < 8; r++)
#pragma unroll
        for (int p = 0; p < 4; p++) acc[r][p] = f2{0.f, 0.f};
    for (int e4 = 0; e4 < 32; e4++) {
        float4 xv[8];
#pragma unroll
        for (int r = 0; r < 8; r++)
            xv[r] = *(const float4*)&in[(size_t)(rowbase + r) * DD + 4 * e4];
#pragma unroll
        for (int ee = 0; ee < 4; ee++) {
            int e = 4 * e4 + ee;
            float4 wa = *(const float4*)&wT[e * 132 + 8 * og];
            float4 wb = *(const float4*)&wT[e * 132 + 8 * og + 4];
            f2 w0 = {wa.x, wa.y}, w1 = {wa.z, wa.w}, w2 = {wb.x, wb.y}, w3 = {wb.z, wb.w};
#pragma unroll
            for (int r = 0; r < 8; r++) {
                float x = ((const float*)&xv[r])[ee];
                f2 x2 = {x, x};
                acc[r][0] = __builtin_elementwise_fma(x2, w0, acc[r][0]);
                acc[r][1] = __builtin_elementwise_fma(x2, w1, acc[r][1]);
                acc[r][2] = __builtin_elementwise_fma(x2, w2, acc[r][2]);
                acc[r][3] = __builtin_elementwise_fma(x2, w3, acc[r][3]);
            }
        }
    }
    float4 ba = *(const float4*)&bs[8 * og];
    float4 bbv = *(const float4*)&bs[8 * og + 4];
    float ss[8];
#pragma unroll
    for (int r = 0; r < 8; r++) {
        float o0 = fmaxf(acc[r][0].x + ba.x, 0.f);
        float o1 = fmaxf(acc[r][0].y + ba.y, 0.f);
        float o2 = fmaxf(acc[r][1].x + ba.z, 0.f);
        float o3 = fmaxf(acc[r][1].y + ba.w, 0.f);
        float o4 = fmaxf(acc[r][2].x + bbv.x, 0.f);
        float o5 = fmaxf(acc[r][2].y + bbv.y, 0.f);
        float o6 = fmaxf(acc[r][3].x + bbv.z, 0.f);
        float o7 = fmaxf(acc[r][3].y + bbv.w, 0.f);
        float4 s1 = {o0, o1, o2, o3}, s2 = {o4, o5, o6, o7};
        float* op = out + (size_t)(rowbase + r) * DD + 8 * og;
        *(float4*)op = s1;
        *(float4*)(op + 4) = s2;
        ss[r] = o0 * o0 + o1 * o1 + o2 * o2 + o3 * o3 + o4 * o4 + o5 * o5 + o6 * o6 + o7 * o7;
    }
    if (inv_out) {
#pragma unroll
        for (int r = 0; r < 8; r++) {
            ss[r] += __shfl_xor(ss[r], 1, 64);
            ss[r] += __shfl_xor(ss[r], 2, 64);
            ss[r] += __shfl_xor(ss[r], 4, 64);
            ss[r] += __shfl_xor(ss[r], 8, 64);
        }
#pragma unroll
        for (int r = 0; r < 8; r++)
            if (og == r) inv_out[rowbase + r] = 1.0f / fmaxf(sqrtf(ss[r]), 1e-12f);
    }
}

__global__ __launch_bounds__(256) void lin_kernel(const float* __restrict__ in, const float* __restrict__ W,
                                                  const float* __restrict__ bias, float* __restrict__ out,
                                                  float* __restrict__ inv_out) {
    __shared__ float wT[DD * 132];
    __shared__ float bs[DD];
    linear_body(wT, bs, in, W, bias, out, inv_out, blockIdx.x);
}

__global__ __launch_bounds__(256) void qkv_all(const float* __restrict__ x,
                                               const float* __restrict__ Wq, const float* __restrict__ bq,
                                               const float* __restrict__ Wk, const float* __restrict__ bk,
                                               const float* __restrict__ Wv, const float* __restrict__ bv,
                                               float* __restrict__ q, float* __restrict__ k, float* __restrict__ v) {
    __shared__ float wT[DD * 132];
    __shared__ float bs[DD];
    int sel = blockIdx.x / 176, blk = blockIdx.x % 176;
    const float* W = (sel == 0) ? Wq : (sel == 1) ? Wk : Wv;
    const float* B = (sel == 0) ? bq : (sel == 1) ? bk : bv;
    float* O = (sel == 0) ? q : (sel == 1) ? k : v;
    linear_body(wT, bs, x, W, B, O, nullptr, blk);
}

// ---------------- L=512 attention, NR=4 rows/lane (two f2 row-pairs) ----------------
// 512 threads = 8 waves = 2 qw x 4 kg. Lane owns rows r0,r0+64 (pair0), r0+128,r0+192
// (pair1), r0 = qw*256+lane. K/V broadcast from LDS; LDS inst count = rows*keys*8/(NR*64)
// -> NR=4 halves the ds_read_b128 count vs NR=2 (the measured bottleneck).
// Softmax without max-shift: algebraically identical; scores are tiny relu-dots/4.
__device__ __forceinline__ void attn512_v6(float* __restrict__ sm,
                                           const float* __restrict__ q, const float* __restrict__ k,
                                           const float* __restrict__ v, float* __restrict__ y,
                                           int b, int h) {
    float* ks = sm;
    float* vs = sm + 512 * 16;
    int t = threadIdx.x;
    const size_t base = (size_t)b * 512 * DD + h * 16;
    for (int i = t; i < 512 * 4; i += 512) {
        int j = i >> 2, c = i & 3;
        *(float4*)&ks[j * 16 + 4 * c] = *(const float4*)&k[base + (size_t)j * DD + 4 * c];
        *(float4*)&vs[j * 16 + 4 * c] = *(const float4*)&v[base + (size_t)j * DD + 4 * c];
    }
    int w = t >> 6, lane = t & 63;
    int kg = w & 3, qw = w >> 2;
    int r0 = qw * 256 + lane;
    f2 qv[2][16];
#pragma unroll
    for (int p = 0; p < 2; p++) {
        const float* qa = q + base + (size_t)(r0 + p * 128) * DD;
        const float* qb2 = qa + 64 * DD;
#pragma unroll
        for (int c = 0; c < 4; c++) {
            float4 va = *(const float4*)(qa + 4 * c);
            float4 vb = *(const float4*)(qb2 + 4 * c);
            qv[p][4 * c + 0] = f2{va.x * 0.25f, vb.x * 0.25f};
            qv[p][4 * c + 1] = f2{va.y * 0.25f, vb.y * 0.25f};
            qv[p][4 * c + 2] = f2{va.z * 0.25f, vb.z * 0.25f};
            qv[p][4 * c + 3] = f2{va.w * 0.25f, vb.w * 0.25f};
        }
    }
    f2 acc[2][16];
    f2 l2[2] = {f2{0.f, 0.f}, f2{0.f, 0.f}};
#pragma unroll
    for (int p = 0; p < 2; p++)
#pragma unroll
        for (int e = 0; e < 16; e++) acc[p][e] = f2{0.f, 0.f};
    __syncthreads();
    int j0 = kg * 128;
    for (int j = j0; j < j0 + 128; j++) {
        float kk[16], vv[16];
#pragma unroll
        for (int c = 0; c < 4; c++) {
            *(float4*)&kk[4 * c] = *(const float4*)&ks[j * 16 + 4 * c];
            *(float4*)&vv[4 * c] = *(const float4*)&vs[j * 16 + 4 * c];
        }
        f2 d0a = qv[0][0] * f2{kk[0], kk[0]};
        f2 d1a = qv[0][1] * f2{kk[1], kk[1]};
        f2 d0b = qv[1][0] * f2{kk[0], kk[0]};
        f2 d1b = qv[1][1] * f2{kk[1], kk[1]};
#pragma unroll
        for (int e = 2; e < 16; e += 2) {
            d0a = __builtin_elementwise_fma(qv[0][e], f2{kk[e], kk[e]}, d0a);
            d1a = __builtin_elementwise_fma(qv[0][e + 1], f2{kk[e + 1], kk[e + 1]}, d1a);
            d0b = __builtin_elementwise_fma(qv[1][e], f2{kk[e], kk[e]}, d0b);
            d1b = __builtin_elementwise_fma(qv[1][e + 1], f2{kk[e + 1], kk[e + 1]}, d1b);
        }
        f2 da = d0a + d1a, db = d0b + d1b;
        f2 pa = {__expf(da.x), __expf(da.y)};
        f2 pb = {__expf(db.x), __expf(db.y)};
        l2[0] += pa;
        l2[1] += pb;
#pragma unroll
        for (int e = 0; e < 16; e++) {
            f2 ve = {vv[e], vv[e]};
            acc[0][e] = __builtin_elementwise_fma(pa, ve, acc[0][e]);
            acc[1][e] = __builtin_elementwise_fma(pb, ve, acc[1][e]);
        }
    }
    __syncthreads();   // staging dead; reuse sm for partials: 512 rows x 20 floats = 40 KB
#pragma unroll
    for (int g = 1; g < 4; g++) {
        if (kg == g) {
#pragma unroll
            for (int p = 0; p < 2; p++) {
                int ra = r0 + p * 128;
                float* pa = &sm[ra * 20];
                float* pb = &sm[(ra + 64) * 20];
#pragma unroll
                for (int e = 0; e < 16; e++) { pa[e] = acc[p][e].x; pb[e] = acc[p][e].y; }
                pa[16] = l2[p].x;
                pb[16] = l2[p].y;
            }
        }
        __syncthreads();
        if (kg == 0) {
#pragma unroll
            for (int p = 0; p < 2; p++) {
                int ra = r0 + p * 128;
                const float* pa = &sm[ra * 20];
                const float* pb = &sm[(ra + 64) * 20];
#pragma unroll
                for (int e = 0; e < 16; e++) { acc[p][e].x += pa[e]; acc[p][e].y += pb[e]; }
                l2[p].x += pa[16];
                l2[p].y += pb[16];
            }
        }
        __syncthreads();
    }
    if (kg == 0) {
#pragma unroll
        for (int p = 0; p < 2; p++) {
            float ix = 1.0f / l2[p].x, iy = 1.0f / l2[p].y;
            float o0[16], o1[16];
#pragma unroll
            for (int e = 0; e < 16; e++) { o0[e] = acc[p][e].x * ix; o1[e] = acc[p][e].y * iy; }
            float* yp0 = y + base + (size_t)(r0 + p * 128) * DD;
            float* yp1 = yp0 + 64 * DD;
#pragma unroll
            for (int c = 0; c < 4; c++) {
                *(float4*)(yp0 + 4 * c) = *(const float4*)&o0[4 * c];
                *(float4*)(yp1 + 4 * c) = *(const float4*)&o1[4 * c];
            }
        }
    }
}

// ---------------- small-L attention (e-split, 8 waves) ----------------
template <int L, int NQ>
__device__ __forceinline__ void attn_body(float* __restrict__ sm, const float* __restrict__ q,
                                          const float* __restrict__ k, const float* __restrict__ v,
                                          float* __restrict__ y, int b, int h) {
    constexpr int WAVES = 8;
    constexpr int WQ = L / (32 * NQ);
    constexpr int KG = WAVES / WQ;
    constexpr int KPG = L / KG;
    float* ks = sm;
    float* vs = sm + L * 16;
    int t = threadIdx.x;
    const size_t base = (size_t)b * L * DD + h * 16;
    for (int i = t; i < L * 4; i += 512) {
        int j = i >> 2, c = i & 3;
        *(float4*)&ks[j * 16 + 4 * c] = *(const float4*)&k[base + (size_t)j * DD + 4 * c];
        *(float4*)&vs[j * 16 + 4 * c] = *(const float4*)&v[base + (size_t)j * DD + 4 * c];
    }
    int w = t >> 6, lane = t & 63;
    int ls = lane & 31, eh = lane >> 5;
    int kg = w % KG, qw = w / KG;
    int qb2 = qw * 32 * NQ;
    f2 qv[NQ][4];
#pragma unroll
    for (int n = 0; n < NQ; n++) {
        int qr = qb2 + ls + 32 * n;
        const float* qp = q + base + (size_t)qr * DD + eh * 8;
        float4 a = *(const float4*)qp;
        float4 b4 = *(const float4*)(qp + 4);
        qv[n][0] = f2{a.x, a.y};   qv[n][1] = f2{a.z, a.w};
        qv[n][2] = f2{b4.x, b4.y}; qv[n][3] = f2{b4.z, b4.w};
    }
    f2 acc[NQ][4];
    float l[NQ];
#pragma unroll
    for (int n = 0; n < NQ; n++) {
#pragma unroll
        for (int m = 0; m < 4; m++) acc[n][m] = f2{0.f, 0.f};
        l[n] = 0.f;
    }
    __syncthreads();
    for (int j = kg * KPG; j < (kg + 1) * KPG; j++) {
        float4 ka = *(const float4*)&ks[j * 16 + eh * 8];
        float4 kb2 = *(const float4*)&ks[j * 16 + eh * 8 + 4];
        float4 va = *(const float4*)&vs[j * 16 + eh * 8];
        float4 vb2 = *(const float4*)&vs[j * 16 + eh * 8 + 4];
        f2 kk0 = {ka.x, ka.y}, kk1 = {ka.z, ka.w}, kk2 = {kb2.x, kb2.y}, kk3 = {kb2.z, kb2.w};
        f2 vv0 = {va.x, va.y}, vv1 = {va.z, va.w}, vv2 = {vb2.x, vb2.y}, vv3 = {vb2.z, vb2.w};
#pragma unroll
        for (int n = 0; n < NQ; n++) {
            f2 d2 = qv[n][0] * kk0;
            d2 = __builtin_elementwise_fma(qv[n][1], kk1, d2);
            d2 = __builtin_elementwise_fma(qv[n][2], kk2, d2);
            d2 = __builtin_elementwise_fma(qv[n][3], kk3, d2);
            float sh = d2.x + d2.y;
            float s = sh + __shfl_xor(sh, 32, 64);
            float p = __expf(s * 0.25f);
            l[n] += p;
            f2 p2 = {p, p};
            acc[n][0] = __builtin_elementwise_fma(p2, vv0, acc[n][0]);
            acc[n][1] = __builtin_elementwise_fma(p2, vv1, acc[n][1]);
            acc[n][2] = __builtin_elementwise_fma(p2, vv2, acc[n][2]);
            acc[n][3] = __builtin_elementwise_fma(p2, vv3, acc[n][3]);
        }
    }
    __syncthreads();
    if (kg > 0) {
#pragma unroll
        for (int n = 0; n < NQ; n++) {
            int qr = qb2 + ls + 32 * n;
            float* pp = &sm[((kg - 1) * L + qr) * 20 + eh * 10];
            *(f2*)&pp[0] = acc[n][0];
            *(f2*)&pp[2] = acc[n][1];
            *(f2*)&pp[4] = acc[n][2];
            *(f2*)&pp[6] = acc[n][3];
            pp[8] = l[n];
        }
    }
    __syncthreads();
    if (kg == 0) {
#pragma unroll
        for (int n = 0; n < NQ; n++) {
            int qr = qb2 + ls + 32 * n;
            f2 a0 = acc[n][0], a1 = acc[n][1], a2 = acc[n][2], a3 = acc[n][3];
            float lt = l[n];
#pragma unroll
            for (int g = 1; g < KG; g++) {
                const float* pp = &sm[((g - 1) * L + qr) * 20 + eh * 10];
                a0 += *(const f2*)&pp[0];
                a1 += *(const f2*)&pp[2];
                a2 += *(const f2*)&pp[4];
                a3 += *(const f2*)&pp[6];
                lt += pp[8];
            }
            float inv = 1.0f / lt;
            float4 o1 = {a0.x * inv, a0.y * inv, a1.x * inv, a1.y * inv};
            float4 o2 = {a2.x * inv, a2.y * inv, a3.x * inv, a3.y * inv};
            float* yp = y + base + (size_t)qr * DD + eh * 8;
            *(float4*)yp = o1;
            *(float4*)(yp + 4) = o2;
        }
    }
}

// XCD swizzle: h = local>>5, b = local&31 -> all 8 heads of a batch land on the
// same XCD (XCD = blk % 8 = b % 8), so K/V L2 lines are fully reused.
__global__ __launch_bounds__(512, 2) void attn_all(const float* __restrict__ qb_, const float* __restrict__ kb_,
                                                   const float* __restrict__ vb_, float* __restrict__ yb_) {
    __shared__ float sm[16384];            // 64 KB
    int blk = blockIdx.x;
    if (blk < 256) {
        const size_t off = (size_t)(ROWS_DCQ + ROWS_D) * DD;
        attn512_v6(sm, qb_ + off, kb_ + off, vb_ + off, yb_ + off, blk & 31, blk >> 5);
    } else if (blk < 512) {
        int local = blk - 256;
        attn_body<128, 1>(sm, qb_, kb_, vb_, yb_, local & 31, local >> 5);
    } else {
        int local = blk - 512;
        const size_t off = (size_t)ROWS_DCQ * DD;
        attn_body<64, 1>(sm, qb_ + off, kb_ + off, vb_ + off, yb_ + off, local & 31, local >> 5);
    }
}

// ---------------- KNRM core: register-tiled sims + gaussian kernels ----------------
template <int QPT, int DPT>
__device__ void knrm_core(float* __restrict__ sm,
                          const float* __restrict__ Q, const float* __restrict__ invQ,
                          const float* __restrict__ mq, int QL, int q0, int qbase,
                          const float* __restrict__ D, const float* __restrict__ invD,
                          const float* __restrict__ md, int DL, int dbase, int mdbase,
                          float* __restrict__ out) {
    constexpr int QT = QPT * 16, DT = DPT * 16;
    float* qtile = sm;
    float* dtile = qtile + QT * 132;
    float* mdv = dtile + DT * 132;
    float* red = mdv + DT;
    float* outred = red + 4 * 16 * QPT * 11;
    const float MUc[11] = {1.0f, 0.9f, 0.7f, 0.5f, 0.3f, 0.1f, -0.1f, -0.3f, -0.5f, -0.7f, -0.9f};
    const float NC[11]  = {-500000.0f, -50.f, -50.f, -50.f, -50.f, -50.f, -50.f, -50.f, -50.f, -50.f, -50.f};
    int t = threadIdx.x;
    int tq = t & 15, td = t >> 4;
    if (t < 11) outred[t] = 0.f;
    for (int i = t; i < QT * 32; i += 256) {
        int r = i >> 5, c = i & 31;
        int qrow = q0 + r;
        float4 val = make_float4(0.f, 0.f, 0.f, 0.f);
        if (qrow < QL) {
            float s = invQ[qbase + qrow];
            float4 g = *(const float4*)(Q + (size_t)(qbase + qrow) * DD + 4 * c);
            val = make_float4(g.x * s, g.y * s, g.z * s, g.w * s);
        }
        *(float4*)&qtile[r * 132 + 4 * c] = val;
    }
    float ps[QPT][11];
#pragma unroll
    for (int i = 0; i < QPT; i++)
#pragma unroll
        for (int kk = 0; kk < 11; kk++) ps[i][kk] = 0.f;

    for (int d0 = 0; d0 < DL; d0 += DT) {
        for (int i = t; i < DT * 32; i += 256) {
            int r = i >> 5, c = i & 31;
            int drow = d0 + r;
            float4 val = make_float4(0.f, 0.f, 0.f, 0.f);
            if (drow < DL) {
                float s = invD[dbase + drow];
                float4 g = *(const float4*)(D + (size_t)(dbase + drow) * DD + 4 * c);
                val = make_float4(g.x * s, g.y * s, g.z * s, g.w * s);
            }
            *(float4*)&dtile[r * 132 + 4 * c] = val;
        }
        if (t < DT) mdv[t] = (d0 + t < DL) ? md[mdbase + d0 + t] : 0.f;
        __syncthreads();
        float dot[QPT][DPT];
#pragma unroll
        for (int i = 0; i < QPT; i++)
#pragma unroll
            for (int j = 0; j < DPT; j++) dot[i][j] = 0.f;
#pragma unroll 2
        for (int e4 = 0; e4 < 32; e4++) {
            float4 qv[QPT], dv[DPT];
#pragma unroll
            for (int i = 0; i < QPT; i++) qv[i] = *(const float4*)&qtile[(tq + 16 * i) * 132 + 4 * e4];
#pragma unroll
            for (int j = 0; j < DPT; j++) dv[j] = *(const float4*)&dtile[(td + 16 * j) * 132 + 4 * e4];
#pragma unroll
            for (int i = 0; i < QPT; i++)
#pragma unroll
                for (int j = 0; j < DPT; j++)
                    dot[i][j] += qv[i].x * dv[j].x + qv[i].y * dv[j].y + qv[i].z * dv[j].z + qv[i].w * dv[j].w;
        }
#pragma unroll
        for (int j = 0; j < DPT; j++) {
            float m = mdv[td + 16 * j];
#pragma unroll
            for (int i = 0; i < QPT; i++) {
                float sim = dot[i][j];
#pragma unroll
                for (int kk = 0; kk < 11; kk++) {
                    float df = sim - MUc[kk];
                    ps[i][kk] = fmaf(__expf(df * df * NC[kk]), m, ps[i][kk]);
                }
            }
        }
        __syncthreads();
    }
#pragma unroll
    for (int i = 0; i < QPT; i++)
#pragma unroll
        for (int kk = 0; kk < 11; kk++) {
            ps[i][kk] += __shfl_xor(ps[i][kk], 16, 64);
            ps[i][kk] += __shfl_xor(ps[i][kk], 32, 64);
        }
    int w = t >> 6;
    if ((t & 63) < 16) {
#pragma unroll
        for (int i = 0; i < QPT; i++)
#pragma unroll
            for (int kk = 0; kk < 11; kk++) red[(w * 16 + tq) * (QPT * 11) + i * 11 + kk] = ps[i][kk];
    }
    __syncthreads();
    for (int i = t; i < 16 * QPT * 11; i += 256) {
        int tq2 = i / (QPT * 11);
        int rem = i - tq2 * (QPT * 11);
        int qi = rem / 11, kk = rem - qi * 11;
        float s = red[(0 * 16 + tq2) * (QPT * 11) + qi * 11 + kk] + red[(1 * 16 + tq2) * (QPT * 11) + qi * 11 + kk]
                + red[(2 * 16 + tq2) * (QPT * 11) + qi * 11 + kk] + red[(3 * 16 + tq2) * (QPT * 11) + qi * 11 + kk];
        int qrow = q0 + tq2 + 16 * qi;
        if (qrow < QL) {
            float lps = logf(fmaxf(s, 1e-10f)) * mq[qbase + qrow] * 0.01f;
            atomicAdd(&outred[kk], lps);
        }
    }
    __syncthreads();
    if (t < 11) atomicAdd(&out[t], outred[t]);
}

__global__ __launch_bounds__(256) void knrm_all(
    const float* __restrict__ eq, const float* __restrict__ inv_eq, const float* __restrict__ mask_q,
    const float* __restrict__ ed, const float* __restrict__ inv_ed, const float* __restrict__ mask_d,
    const float* __restrict__ eb, const float* __restrict__ inv_eb, const float* __restrict__ mask_db,
    const float* __restrict__ enc_d, const float* __restrict__ inv_encd,
    const float* __restrict__ enc_b, const float* __restrict__ inv_encb,
    const float* __restrict__ enc_dcq, const float* __restrict__ inv_encdcq, const float* __restrict__ mask_dcq,
    float* __restrict__ qdk, float* __restrict__ qbk,
    float* __restrict__ kq, float* __restrict__ kd, float* __restrict__ kb) {
    __shared__ float sm[14155];
    int blk = blockIdx.x;
    if (blk < 32) {
        int b = blk;
        knrm_core<2, 4>(sm, eq, inv_eq, mask_q, QL_, 0, b * QL_, ed, inv_ed, mask_d, DL_, b * DL_, b * DL_, qdk + b * 11);
    } else if (blk < 64) {
        int b = blk - 32;
        knrm_core<2, 4>(sm, eq, inv_eq, mask_q, QL_, 0, b * QL_, eb, inv_eb, mask_db, BL_, b * BL_, b * BL_, qbk + b * 11);
    } else {
        int u = blk - 64;
        int sub = u % 10;
        int ib = u / 10;
        int b = ib & 31, inst = ib >> 5;
        int dbase = b * (MN_ * ML_) + inst * ML_;
        if (sub == 0)
            knrm_core<4, 1>(sm, eq, inv_eq, mask_q, QL_, 0, b * QL_, enc_dcq, inv_encdcq, mask_dcq, ML_, dbase, dbase,
                            kq + (size_t)(inst * BB + b) * 11);
        else if (sub == 1)
            knrm_core<4, 1>(sm, enc_d, inv_encd, mask_d, DL_, 0, b * DL_, enc_dcq, inv_encdcq, mask_dcq, ML_, dbase, dbase,
                            kd + (size_t)(inst * BB + b) * 11);
        else
            knrm_core<4, 1>(sm, enc_b, inv_encb, mask_db, BL_, (sub - 2) * 64, b * BL_, enc_dcq, inv_encdcq, mask_dcq, ML_,
                            dbase, dbase, kb + (size_t)(inst * BB + b) * 11);
    }
}

// ---------------- final combine ----------------
__device__ inline float dot11(const float* w, const float* x) {
    float s = 0.f;
#pragma unroll
    for (int k = 0; k < 11; k++) s += w[k] * x[k];
    return s;
}

__global__ void final_kernel(const float* __restrict__ qdk, const float* __restrict__ qbk,
                             const float* __restrict__ kq, const float* __restrict__ kd,
                             const float* __restrict__ kb,
                             const float* qdW, const float* qdb, const float* qbW, const float* qbb,
                             const float* qcqW, const float* qcqb, const float* dcqW, const float* dcqb,
                             const float* bcqW, const float* bcqb, const float* expW, const float* expb,
                             const float* combW, const float* combb, float* __restrict__ out) {
    int b = threadIdx.x;
    if (b >= BB) return;
    float qd = tanhf(dot11(qdW, qdk + b * 11) + qdb[0]);
    float qb = tanhf(dot11(qbW, qbk + b * 11) + qbb[0]);
    float qcqd = 0.f, qcqb2 = 0.f;
    for (int i = 0; i < MN_; i++) {
        int base = (i * BB + b) * 11;
        float r  = tanhf(dot11(qcqW, kq + base) + qcqb[0]);
        float da = tanhf(dot11(dcqW, kd + base) + dcqb[0]);
        float ba = tanhf(dot11(bcqW, kb + base) + bcqb[0]);
        qcqd += r * da;
        qcqb2 += r * ba;
    }
    float qcq = expW[0] * qcqd + expW[1] * qcqb2 + expb[0];
    out[b] = tanhf(combW[0] * qd + combW[1] * qb + combW[2] * qcq + combb[0]);
}

extern "C" void kernel_launch(void* const* d_in, const int* in_sizes, int n_in,
                              void* d_out, int out_size, void* d_ws, size_t ws_size,
                              hipStream_t stream) {
    const int*   in_q    = (const int*)d_in[0];
    const int*   in_d    = (const int*)d_in[1];
    const int*   in_dcq  = (const int*)d_in[2];
    const int*   in_db   = (const int*)d_in[3];
    const float* mask_q  = (const float*)d_in[4];
    const float* mask_d  = (const float*)d_in[5];
    const float* mask_dcq= (const float*)d_in[6];
    const float* mask_db = (const float*)d_in[7];
    const float* emb     = (const float*)d_in[8];
    const float* Wq = (const float*)d_in[9];   const float* bq = (const float*)d_in[10];
    const float* Wk = (const float*)d_in[11];  const float* bk = (const float*)d_in[12];
    const float* Wv = (const float*)d_in[13];  const float* bv = (const float*)d_in[14];
    const float* Wo = (const float*)d_in[15];  const float* bo = (const float*)d_in[16];
    const float* tW = (const float*)d_in[17];  const float* tb = (const float*)d_in[18];
    const float* qdW = (const float*)d_in[19]; const float* qdb = (const float*)d_in[20];
    const float* qbW = (const float*)d_in[21]; const float* qbb = (const float*)d_in[22];
    const float* qcqW = (const float*)d_in[23];const float* qcqb = (const float*)d_in[24];
    const float* dcqW = (const float*)d_in[25];const float* dcqb = (const float*)d_in[26];
    const float* bcqW = (const float*)d_in[27];const float* bcqb = (const float*)d_in[28];
    const float* expW = (const float*)d_in[29];const float* expb = (const float*)d_in[30];
    const float* combW = (const float*)d_in[31];const float* combb = (const float*)d_in[32];
    float* out = (float*)d_out;

    float* ws = (float*)d_ws;
    size_t off = 0;
    auto alloc = [&](size_t n) { float* p = ws + off; off += n; return p; };
    float* x_all = alloc((size_t)R_GATHER * DD);   // [dcq|d|b|eq] embeddings / projected dcq
    float* qbuf  = alloc((size_t)R_ALL * DD);      // q proj; attn writes y in-place here
    float* kbuf  = alloc((size_t)R_ALL * DD);      // gather tmp -> k proj -> enc_all
    float* vbuf  = alloc((size_t)R_ALL * DD);
    float* inv_eq  = alloc(ROWS_EQ);
    float* inv_ed  = alloc(ROWS_D);
    float* inv_eb  = alloc(ROWS_B);
    float* inv_enc = alloc(R_ALL);
    float* qdk = alloc(BB * 11);                   // knrm atomic outs (contiguous, zeroed in gather)
    float* qbk = alloc(BB * 11);
    float* kq  = alloc(MN_ * BB * 11);
    float* kd  = alloc(MN_ * BB * 11);
    float* kb  = alloc(MN_ * BB * 11);
    (void)ws_size; (void)in_sizes; (void)n_in; (void)out_size;

    const float* eq      = x_all + (size_t)R_ALL * DD;
    const float* ed      = x_all + (size_t)ROWS_DCQ * DD;
    const float* eb      = x_all + (size_t)(ROWS_DCQ + ROWS_D) * DD;
    float* enc_all = kbuf;
    const float* enc_dcq = enc_all;
    const float* enc_d   = enc_all + (size_t)ROWS_DCQ * DD;
    const float* enc_b   = enc_all + (size_t)(ROWS_DCQ + ROWS_D) * DD;
    const float* inv_encdcq = inv_enc;
    const float* inv_encd   = inv_enc + ROWS_DCQ;
    const float* inv_encb   = inv_enc + ROWS_DCQ + ROWS_D;

    // 1. gathers + emb norms + zero knrm accumulators (dcq raw emb -> kbuf tmp)
    gather_all<<<2932, 256, 0, stream>>>(in_q, in_d, in_dcq, in_db, emb,
                                         x_all, kbuf, inv_eq, inv_ed, inv_eb, qdk, 9152);
    // 2. t-projection: raw dcq emb (kbuf[0:4096]) -> x_all[0:4096]
    lin_kernel<<<ROWS_DCQ / 128, 256, 0, stream>>>(kbuf, tW, tb, x_all, nullptr);
    // 3. q/k/v projections over all 22528 rows in one launch
    qkv_all<<<3 * (R_ALL / 128), 256, 0, stream>>>(x_all, Wq, bq, Wk, bk, Wv, bv, qbuf, kbuf, vbuf);
    // 4. all three attentions in one launch; y written in-place into qbuf
    attn_all<<<768, 512, 0, stream>>>(qbuf, kbuf, vbuf, qbuf);
    // 5. out-projection over all rows + fused enc norms (kbuf becomes enc_all)
    lin_kernel<<<R_ALL / 128, 256, 0, stream>>>(qbuf, Wo, bo, enc_all, inv_enc);
    // 6. all 26 KNRM reductions
    knrm_all<<<2624, 256, 0, stream>>>(eq, inv_eq, mask_q, ed, inv_ed, mask_d, eb, inv_eb, mask_db,
                                       enc_d, inv_encd, enc_b, inv_encb, enc_dcq, inv_encdcq, mask_dcq,
                                       qdk, qbk, kq, kd, kb);
    // 7. final combine
    final_kernel<<<1, 64, 0, stream>>>(qdk, qbk, kq, kd, kb,
                                       qdW, qdb, qbW, qbb, qcqW, qcqb, dcqW, dcqb,
                                       bcqW, bcqb, expW, expb, combW, combb, out);
}